// Round 6
// baseline (2462.170 us; speedup 1.0000x reference)
//
#include <hip/hip_runtime.h>
#include <hip/hip_bf16.h>
#include <math.h>

#define N_IMG 4
#define CIN 512
#define NANCH 36864          // 64*64*9
#define PRE_NMS_N 3000
#define POST_NMS_N 300
#define NWORD 47             // ceil(3000/64)

// out layout (floats)
#define OFF_SCORES 589824
#define OFF_ROIS   884736
#define OFF_VALID  889536
#define OFF_ANCH   890736

typedef _Float16 f16x8 __attribute__((ext_vector_type(8)));
typedef float f32x4 __attribute__((ext_vector_type(4)));

__device__ __forceinline__ int swz(int p) { return (p + (p >> 2)) & 3; }

__device__ __forceinline__ unsigned long long rdlane64(unsigned long long v, int l) {
  unsigned int lo = (unsigned int)__builtin_amdgcn_readlane((int)(unsigned int)v, l);
  unsigned int hi = (unsigned int)__builtin_amdgcn_readlane((int)(unsigned int)(v >> 32), l);
  return (((unsigned long long)hi) << 32) | lo;
}

// ---------------- K0w: W1 [co][ci][tap] -> Wt_{h,l}[tap][co][ci], scaled x64 ----------
__global__ __launch_bounds__(256) void k0w_convert(
    const float* __restrict__ W1, _Float16* __restrict__ wth, _Float16* __restrict__ wtl) {
  const int tap = blockIdx.x, co0 = blockIdx.y * 32;
  for (int idx = threadIdx.x; idx < 32 * 512; idx += 256) {
    int col = idx >> 9, ci = idx & 511;
    float v = W1[(size_t)(co0 + col) * 4608 + ci * 9 + tap] * 64.0f;
    _Float16 hi = (_Float16)v;
    float lo = v - (float)hi;
    size_t o = ((size_t)(tap * 512 + co0 + col) << 9) + ci;
    wth[o] = hi; wtl[o] = (_Float16)lo;
  }
}

// ---------------- K0x: x [ci][64x64] -> padded xh/xl [66*66][512] f16 split -----------
__global__ __launch_bounds__(256) void k0x_convert(
    const float* __restrict__ x, _Float16* __restrict__ xh, _Float16* __restrict__ xl,
    int img) {
  const int bx = blockIdx.x, ci0 = blockIdx.y * 64;
  const int tid = threadIdx.x;
  if (bx < 64) {
    __shared__ float t[64][65];
    const float* xp = x + ((size_t)img * 512 + ci0) * 4096 + bx * 64;
    for (int idx = tid; idx < 4096; idx += 256) {
      int ci_l = idx >> 6, col = idx & 63;
      t[ci_l][col] = xp[(size_t)ci_l * 4096 + col];
    }
    __syncthreads();
    for (int idx = tid; idx < 4096; idx += 256) {
      int col = idx >> 6, ci_l = idx & 63;
      float v = t[ci_l][col];
      _Float16 hi = (_Float16)v;
      float lo = v - (float)hi;
      size_t o = (((size_t)(bx + 1) * 66 + col + 1) << 9) + ci0 + ci_l;
      xh[o] = hi; xl[o] = (_Float16)lo;
    }
  } else {
    for (int tt = tid; tt < 52 * 64; tt += 256) {
      int pl = tt >> 6, ci_l = tt & 63;
      int p = (bx - 64) * 52 + pl;
      if (p < 260) {
        int pp;
        if (p < 66) pp = p;
        else if (p < 132) pp = 65 * 66 + (p - 66);
        else if (p < 196) pp = (p - 132 + 1) * 66;
        else pp = (p - 196 + 1) * 66 + 65;
        size_t o = ((size_t)pp << 9) + ci0 + ci_l;
        xh[o] = (_Float16)0.f; xl[o] = (_Float16)0.f;
      }
    }
  }
}

// ---------------- K1: conv3x3 MFMA implicit GEMM; px-major grid, dist-2 prefetch ------
// grid (32 px-tiles, 8 co-groups): XCD = blockid%8 = px%8 -> per-XCD A window ~1MB L2-hot
__global__ __launch_bounds__(256) void k1_gemm(
    const _Float16* __restrict__ xh, const _Float16* __restrict__ xl,
    const _Float16* __restrict__ wth, const _Float16* __restrict__ wtl,
    const float* __restrict__ b1, float* __restrict__ h_out) {
  const int tid = threadIdx.x;
  const int px0 = blockIdx.x * 128;
  const int co0 = blockIdx.y * 64;
  const int y0 = px0 >> 6;

  __shared__ __align__(16) _Float16 AsL[4][4096];
  __shared__ __align__(16) _Float16 BsL[4][2048];

  const int lane = tid & 63, q = lane >> 4, lr = lane & 15;
  const int wid = tid >> 6, wm = wid & 1, wn = wid >> 1;

  int abase[2];
  #pragma unroll
  for (int it = 0; it < 2; ++it) {
    int s = it * 256 + tid;
    int pxl = s >> 2, cpos = s & 3;
    int c = cpos ^ swz(pxl);
    int row = pxl >> 6, xcol = pxl & 63;
    abase[it] = (((y0 + row) * 66 + xcol) << 9) + c * 8;
  }
  const int bcol = tid >> 2;
  const int bch = (tid & 3) ^ swz(bcol);
  const int bbase = ((co0 + bcol) << 9) + bch * 8;

  const int DD[9] = {0, 1, 2, 66, 67, 68, 132, 133, 134};

  f32x4 acc[4][2] = {};
  float4 rah[2], ral[2], rbh, rbl;

  // t=0 -> LDS buf0 directly
  #pragma unroll
  for (int it = 0; it < 2; ++it) {
    float4 h0 = *(const float4*)(xh + abase[it]);
    float4 l0 = *(const float4*)(xl + abase[it]);
    *(float4*)&AsL[0][(it * 256 + tid) * 8] = h0;
    *(float4*)&AsL[1][(it * 256 + tid) * 8] = l0;
  }
  {
    float4 bh0 = *(const float4*)(wth + bbase);
    float4 bl0 = *(const float4*)(wtl + bbase);
    *(float4*)&BsL[0][tid * 8] = bh0;
    *(float4*)&BsL[1][tid * 8] = bl0;
  }
  // t=1 (tap=1, cb=0) -> regs
  {
    const int ad = (DD[1] << 9);
    #pragma unroll
    for (int it = 0; it < 2; ++it) {
      rah[it] = *(const float4*)(xh + abase[it] + ad);
      ral[it] = *(const float4*)(xl + abase[it] + ad);
    }
    rbh = *(const float4*)(wth + bbase + 262144);
    rbl = *(const float4*)(wtl + bbase + 262144);
  }

  int tap2 = 2, cb2 = 0;   // position t+2 (tap fastest, cb outer)
  for (int t = 0; t < 144; ++t) {
    __syncthreads();
    const int buf = t & 1;
    float4 nah[2] = {}, nal[2] = {}, nbh = {}, nbl = {};
    const bool pf2 = (t + 2 < 144);
    if (pf2) {
      const int ad = (DD[tap2] << 9) + cb2 * 32;
      #pragma unroll
      for (int it = 0; it < 2; ++it) {
        nah[it] = *(const float4*)(xh + abase[it] + ad);
        nal[it] = *(const float4*)(xl + abase[it] + ad);
      }
      const int bd = tap2 * 262144 + cb2 * 32;
      nbh = *(const float4*)(wth + bbase + bd);
      nbl = *(const float4*)(wtl + bbase + bd);
      ++tap2; if (tap2 == 9) { tap2 = 0; ++cb2; }
    }
    if (t + 1 < 144) {
      const int nb = (t + 1) & 1;
      #pragma unroll
      for (int it = 0; it < 2; ++it) {
        *(float4*)&AsL[nb * 2 + 0][(it * 256 + tid) * 8] = rah[it];
        *(float4*)&AsL[nb * 2 + 1][(it * 256 + tid) * 8] = ral[it];
      }
      *(float4*)&BsL[nb * 2 + 0][tid * 8] = rbh;
      *(float4*)&BsL[nb * 2 + 1][tid * 8] = rbl;
    }
    f16x8 ah[4], al[4], bh[2], bl[2];
    #pragma unroll
    for (int mi = 0; mi < 4; ++mi) {
      int pxl = wm * 64 + mi * 16 + lr;
      int cpr = q ^ swz(pxl);
      ah[mi] = *(const f16x8*)&AsL[buf * 2 + 0][pxl * 32 + cpr * 8];
      al[mi] = *(const f16x8*)&AsL[buf * 2 + 1][pxl * 32 + cpr * 8];
    }
    #pragma unroll
    for (int ni = 0; ni < 2; ++ni) {
      int col = wn * 32 + ni * 16 + lr;
      int cpr = q ^ swz(col);
      bh[ni] = *(const f16x8*)&BsL[buf * 2 + 0][col * 32 + cpr * 8];
      bl[ni] = *(const f16x8*)&BsL[buf * 2 + 1][col * 32 + cpr * 8];
    }
    #pragma unroll
    for (int mi = 0; mi < 4; ++mi)
      #pragma unroll
      for (int ni = 0; ni < 2; ++ni) {
        acc[mi][ni] = __builtin_amdgcn_mfma_f32_16x16x32_f16(ah[mi], bh[ni], acc[mi][ni], 0, 0, 0);
        acc[mi][ni] = __builtin_amdgcn_mfma_f32_16x16x32_f16(ah[mi], bl[ni], acc[mi][ni], 0, 0, 0);
        acc[mi][ni] = __builtin_amdgcn_mfma_f32_16x16x32_f16(al[mi], bh[ni], acc[mi][ni], 0, 0, 0);
      }
    if (pf2) {
      #pragma unroll
      for (int it = 0; it < 2; ++it) { rah[it] = nah[it]; ral[it] = nal[it]; }
      rbh = nbh; rbl = nbl;
    }
  }

  float bb[2];
  #pragma unroll
  for (int ni = 0; ni < 2; ++ni) bb[ni] = b1[co0 + wn * 32 + ni * 16 + lr];
  #pragma unroll
  for (int mi = 0; mi < 4; ++mi)
    #pragma unroll
    for (int ni = 0; ni < 2; ++ni)
      #pragma unroll
      for (int rr = 0; rr < 4; ++rr) {
        int pxl = wm * 64 + mi * 16 + q * 4 + rr;
        int co = co0 + wn * 32 + ni * 16 + lr;
        float v = acc[mi][ni][rr] * 0.015625f + bb[ni];
        h_out[((size_t)(px0 + pxl) << 9) + co] = fmaxf(v, 0.f);
      }
}

// ---------------- K2: 1x1 heads + softmax-fg, K-split x4, 64 blocks/img ---------------
__global__ __launch_bounds__(256) void k2_heads(
    const float* __restrict__ h,
    const float* __restrict__ Wl, const float* __restrict__ bl,
    const float* __restrict__ Ws, const float* __restrict__ bs,
    float* __restrict__ rpn_locs, float* __restrict__ rpn_scores,
    float* __restrict__ fg, int img) {
  const int tid = threadIdx.x;
  const int px0 = blockIdx.x * 64;
  const int pxl = tid & 63, kq = tid >> 6;
  __shared__ float part[4][64][57];
  float acc[54];
  #pragma unroll
  for (int c = 0; c < 54; ++c) acc[c] = 0.f;
  const float* hp = h + ((size_t)(px0 + pxl) << 9) + kq * 128;
  for (int k = 0; k < 128; k += 4) {
    float4 a = *(const float4*)(hp + k);
    #pragma unroll
    for (int ch = 0; ch < 54; ++ch) {
      const float* wr = (ch < 36) ? (Wl + ch * 512) : (Ws + (ch - 36) * 512);
      float4 w = *(const float4*)(wr + kq * 128 + k);
      acc[ch] = fmaf(w.x, a.x, fmaf(w.y, a.y, fmaf(w.z, a.z, fmaf(w.w, a.w, acc[ch]))));
    }
  }
  #pragma unroll
  for (int ch = 0; ch < 54; ++ch) part[kq][pxl][ch] = acc[ch];
  __syncthreads();

  const int cq = kq;
  const int p = px0 + pxl;
  const size_t abase = (size_t)img * NANCH + (size_t)p * 9;
  if (cq < 3) {
    #pragma unroll
    for (int ai = 0; ai < 3; ++ai) {
      int a = cq * 3 + ai;
      float v[4];
      #pragma unroll
      for (int c = 0; c < 4; ++c) {
        int ch = a * 4 + c;
        v[c] = ((part[0][pxl][ch] + part[1][pxl][ch]) + part[2][pxl][ch]) +
               part[3][pxl][ch] + bl[ch];
      }
      float4 lv; lv.x = v[0]; lv.y = v[1]; lv.z = v[2]; lv.w = v[3];
      *(float4*)(rpn_locs + (abase + a) * 4) = lv;
    }
  } else {
    #pragma unroll
    for (int a = 0; a < 9; ++a) {
      int c0 = 36 + 2 * a, c1 = c0 + 1;
      float s0 = ((part[0][pxl][c0] + part[1][pxl][c0]) + part[2][pxl][c0]) +
                 part[3][pxl][c0] + bs[2 * a];
      float s1 = ((part[0][pxl][c1] + part[1][pxl][c1]) + part[2][pxl][c1]) +
                 part[3][pxl][c1] + bs[2 * a + 1];
      float2 sv; sv.x = s0; sv.y = s1;
      *(float2*)(rpn_scores + (abase + a) * 2) = sv;
      float m = fmaxf(s0, s1);
      float e0 = expf(s0 - m), e1 = expf(s1 - m);
      fg[abase + a] = e1 / (e0 + e1);
    }
  }
}

// ---------------- K3: anchors + decode + clip + key ----------------
__global__ void k3_decode(
    const float* __restrict__ locs, const float* __restrict__ fg,
    const int* __restrict__ ihp, const int* __restrict__ iwp,
    float* __restrict__ anchors_out, float4* __restrict__ boxes,
    unsigned long long* __restrict__ keys) {
  int gid = blockIdx.x * 256 + threadIdx.x;
  if (gid >= N_IMG * NANCH) return;
  int n = gid / NANCH, i = gid - n * NANCH;
  int p = i / 9, a = i - p * 9;
  int yy = p >> 6, xx = p & 63;
  int ri = a / 3, si = a - ri * 3;
  const float ratios[3] = {0.5f, 1.0f, 2.0f};
  const float scales[3] = {8.f, 16.f, 32.f};
  float hh = 16.f * scales[si] * sqrtf(ratios[ri]);
  float ww = 16.f * scales[si] * sqrtf(1.0f / ratios[ri]);
  float by1 = 8.f - hh * 0.5f, bx1 = 8.f - ww * 0.5f;
  float by2 = 8.f + hh * 0.5f, bx2 = 8.f + ww * 0.5f;
  float ay1 = yy * 16.f + by1, ax1 = xx * 16.f + bx1;
  float ay2 = yy * 16.f + by2, ax2 = xx * 16.f + bx2;
  if (n == 0) {
    float* ao = anchors_out + (size_t)i * 4;
    ao[0] = ay1; ao[1] = ax1; ao[2] = ay2; ao[3] = ax2;
  }
  const float* lp = locs + ((size_t)n * NANCH + i) * 4;
  float dy = lp[0], dx = lp[1], dh = lp[2], dw = lp[3];
  float ah = ay2 - ay1, aw = ax2 - ax1;
  float acy = ay1 + 0.5f * ah, acx = ax1 + 0.5f * aw;
  float cy = dy * ah + acy, cx = dx * aw + acx;
  float hb = expf(dh) * ah, wb = expf(dw) * aw;
  float imh = (float)ihp[0], imw = (float)iwp[0];
  float y1 = fminf(fmaxf(cy - 0.5f * hb, 0.f), imh);
  float x1 = fminf(fmaxf(cx - 0.5f * wb, 0.f), imw);
  float y2 = fminf(fmaxf(cy + 0.5f * hb, 0.f), imh);
  float x2 = fminf(fmaxf(cx + 0.5f * wb, 0.f), imw);
  bool valid = ((y2 - y1) >= 16.0f) && ((x2 - x1) >= 16.0f);
  float s = valid ? fg[(size_t)n * NANCH + i] : -__builtin_inff();
  boxes[(size_t)n * NANCH + i] = make_float4(y1, x1, y2, x2);
  unsigned int fb = __float_as_uint(s);
  unsigned int mono = (fb & 0x80000000u) ? ~fb : (fb | 0x80000000u);
  keys[(size_t)n * NANCH + i] =
      (((unsigned long long)mono) << 32) | (unsigned int)(~(unsigned int)i);
}

// ---------------- K4: per-image exact top-3000 (sorted desc) ----------------
__global__ __launch_bounds__(1024) void k4_select(
    const unsigned long long* __restrict__ keys, const float4* __restrict__ boxes,
    float4* __restrict__ sboxes, unsigned int* __restrict__ sfin) {
  const int n = blockIdx.x, tid = threadIdx.x;
  const unsigned long long* kk = keys + (size_t)n * NANCH;
  __shared__ unsigned int hist[2048];
  __shared__ unsigned int suf[2048];
  __shared__ unsigned long long sb[4096];
  __shared__ int selb;
  __shared__ unsigned int cnt;
  unsigned long long prefix = 0ull;
  int need = PRE_NMS_N;
  const int shifts[6] = {53, 42, 31, 20, 10, 0};
  const int widths[6] = {11, 11, 11, 11, 10, 10};
  for (int rd = 0; rd < 6; ++rd) {
    const int s = shifts[rd], w = widths[rd];
    const int hib = s + w;
    for (int b = tid; b < 2048; b += 1024) hist[b] = 0u;
    __syncthreads();
    for (int i = tid; i < NANCH; i += 1024) {
      unsigned long long key = kk[i];
      bool match = (hib >= 64) || (((key ^ prefix) >> hib) == 0ull);
      if (match)
        atomicAdd(&hist[(unsigned)((key >> s) & ((1u << w) - 1u))], 1u);
    }
    __syncthreads();
    for (int off = 1; off < 2048; off <<= 1) {
      for (int b = tid; b < 2048; b += 1024)
        suf[b] = hist[b] + ((b + off < 2048) ? hist[b + off] : 0u);
      __syncthreads();
      for (int b = tid; b < 2048; b += 1024) hist[b] = suf[b];
      __syncthreads();
    }
    const int nb = 1 << w;
    for (int b = tid; b < nb; b += 1024) {
      unsigned int sv = hist[b];
      unsigned int nxt = (b + 1 < 2048) ? hist[b + 1] : 0u;
      if (sv >= (unsigned)need && nxt < (unsigned)need) selb = b;
    }
    __syncthreads();
    int bstar = selb;
    unsigned int cgt = (bstar + 1 < 2048) ? hist[bstar + 1] : 0u;
    need -= (int)cgt;
    prefix |= ((unsigned long long)bstar) << s;
    __syncthreads();
  }
  if (tid == 0) cnt = 0u;
  __syncthreads();
  for (int i = tid; i < NANCH; i += 1024) {
    unsigned long long key = kk[i];
    if (key >= prefix) {
      unsigned int pos = atomicAdd(&cnt, 1u);
      if (pos < 4096u) sb[pos] = ~key;
    }
  }
  __syncthreads();
  unsigned int c0 = cnt;
  for (int i = tid; i < 4096; i += 1024)
    if (i >= (int)c0) sb[i] = 0xFFFFFFFFFFFFFFFFull;
  __syncthreads();
  for (int k2 = 2; k2 <= 4096; k2 <<= 1) {
    for (int j = k2 >> 1; j > 0; j >>= 1) {
      for (int t = tid; t < 2048; t += 1024) {
        int i = ((t & ~(j - 1)) << 1) | (t & (j - 1));
        int pp = i + j;
        bool up = ((i & k2) == 0);
        unsigned long long va = sb[i], vb = sb[pp];
        bool sw = up ? (va > vb) : (va < vb);
        if (sw) { sb[i] = vb; sb[pp] = va; }
      }
      __syncthreads();
    }
  }
  const float4* bx = boxes + (size_t)n * NANCH;
  for (int r = tid; r < PRE_NMS_N; r += 1024) {
    unsigned long long key = ~sb[r];
    unsigned int idx = ~((unsigned int)(key & 0xFFFFFFFFull));
    sboxes[(size_t)n * PRE_NMS_N + r] = bx[idx];
    unsigned int hi32 = (unsigned int)(key >> 32);
    sfin[n * PRE_NMS_N + r] = (hi32 > 0x007FFFFFu) ? 1u : 0u;
  }
}

// ---------------- K5: suppression bitmask (wave-per-item, ballot, triangle) -----------
__global__ __launch_bounds__(256) void k5_mask(
    const float4* __restrict__ sboxes, unsigned long long* __restrict__ mask) {
  const int c = blockIdx.x, n = blockIdx.y;
  __shared__ float sy1[3008], sx1[3008], sy2[3008], sx2[3008], sar[3008];
  const int tid = threadIdx.x;
  for (int i = tid; i < PRE_NMS_N; i += 256) {
    float4 b = sboxes[(size_t)n * PRE_NMS_N + i];
    sy1[i] = b.x; sx1[i] = b.y; sy2[i] = b.z; sx2[i] = b.w;
    sar[i] = (b.z - b.x) * (b.w - b.y);
  }
  for (int i = PRE_NMS_N + tid; i < 3008; i += 256) {
    sy1[i] = 0.f; sx1[i] = 0.f; sy2[i] = 0.f; sx2[i] = 0.f; sar[i] = 0.f;
  }
  __syncthreads();
  const int lane = tid & 63, wv = tid >> 6;
  const int nwd = NWORD - c;
  const int nitems = 64 * nwd;
  for (int it = wv; it < nitems; it += 4) {
    int il = it & 63, wd = c + (it >> 6);
    int i = c * 64 + il;
    if (i >= PRE_NMS_N) continue;
    float biy1 = sy1[i], bix1 = sx1[i], biy2 = sy2[i], bix2 = sx2[i], bia = sar[i];
    int j = wd * 64 + lane;
    float y1 = fmaxf(biy1, sy1[j]), x1 = fmaxf(bix1, sx1[j]);
    float y2 = fminf(biy2, sy2[j]), x2 = fminf(bix2, sx2[j]);
    float inter = fmaxf(y2 - y1, 0.f) * fmaxf(x2 - x1, 0.f);
    float uni = bia + sar[j] - inter;
    float iou = (uni > 0.f) ? inter / uni : 0.f;
    bool pr = (j < PRE_NMS_N) && (iou > 0.7f);
    unsigned long long bits = __ballot(pr);
    if (lane == 0)
      mask[((size_t)n * PRE_NMS_N + i) * NWORD + wd] = bits;
  }
}

// ---------------- K6: chunked greedy NMS, LDS-staged slabs, 256 thr, wave0 serial -----
__global__ __launch_bounds__(256) void k6_nms(
    const unsigned long long* __restrict__ mask, const float4* __restrict__ sboxes,
    const unsigned int* __restrict__ sfin,
    float* __restrict__ out_rois, float* __restrict__ out_valid) {
  const int n = blockIdx.x, tid = threadIdx.x;
  const int lane = tid & 63;
  const unsigned long long* M = mask + (size_t)n * PRE_NMS_N * NWORD;
  __shared__ unsigned long long rows[2][64][NWORD];
  __shared__ unsigned long long keepW[NWORD];

  // prefetch chunk 0 -> buf0
  #pragma unroll
  for (int j = 0; j < 12; ++j) {
    int idx = j * 256 + tid;
    if (idx < 64 * NWORD) {
      int row = idx / NWORD, w = idx - row * NWORD;
      rows[0][row][w] = M[(size_t)row * NWORD + w];
    }
  }
  __syncthreads();

  unsigned long long Rw = 0ull;   // wave0 lane w (<NWORD): removed-bits word w
  for (int c = 0; c < NWORD; ++c) {
    const int buf = c & 1;
    const int i0 = c * 64;
    const int nIt = (c == NWORD - 1) ? (PRE_NMS_N - i0) : 64;
    // 1) all threads: issue bulk loads for chunk c+1 (in flight during serial phase)
    unsigned long long pf[12];
    const bool hasNext = (c + 1 < NWORD);
    if (hasNext) {
      const int i1 = (c + 1) * 64;
      #pragma unroll
      for (int j = 0; j < 12; ++j) {
        int idx = j * 256 + tid;
        if (idx < 64 * NWORD) {
          int row = idx / NWORD, w = idx - row * NWORD;
          int gi = i1 + row;
          pf[j] = (gi < PRE_NMS_N) ? M[(size_t)gi * NWORD + w] : 0ull;
        }
      }
    }
    // 2) wave0: serial greedy on chunk c (LDS + registers only)
    if (tid < 64) {
      unsigned long long Dcur = rows[buf][lane][c];   // diag word of row `lane`
      unsigned long long rem = rdlane64(Rw, c);
      unsigned long long und = ~rem;
      if (nIt < 64) und &= ((1ull << nIt) - 1ull);
      unsigned long long kept = 0ull;
      while (und) {
        int b = __builtin_ctzll(und);
        kept |= (1ull << b);
        unsigned long long db = rdlane64(Dcur, b);
        und &= ~db;
        und &= ~(1ull << b);
      }
      if (lane == 0) keepW[c] = kept;
      const bool upd = (lane > c) && (lane < NWORD);
      unsigned long long kk = kept;
      while (kk) {
        int b0 = __builtin_ctzll(kk); kk &= kk - 1ull;
        int b1 = b0, b2 = b0, b3 = b0;
        if (kk) { b1 = __builtin_ctzll(kk); kk &= kk - 1ull; }
        if (kk) { b2 = __builtin_ctzll(kk); kk &= kk - 1ull; }
        if (kk) { b3 = __builtin_ctzll(kk); kk &= kk - 1ull; }
        if (upd) {
          unsigned long long v0 = rows[buf][b0][lane];
          unsigned long long v1 = rows[buf][b1][lane];
          unsigned long long v2 = rows[buf][b2][lane];
          unsigned long long v3 = rows[buf][b3][lane];
          Rw |= (v0 | v1) | (v2 | v3);
        }
      }
    }
    // 3) store prefetched slab into the other buffer
    if (hasNext) {
      #pragma unroll
      for (int j = 0; j < 12; ++j) {
        int idx = j * 256 + tid;
        if (idx < 64 * NWORD) {
          int row = idx / NWORD, w = idx - row * NWORD;
          rows[buf ^ 1][row][w] = pf[j];
        }
      }
    }
    __syncthreads();
  }

  // compaction (wave0 only)
  if (tid < 64) {
    const unsigned int* fin = sfin + n * PRE_NMS_N;
    int running = 0;
    for (int c = 0; c < NWORD; ++c) {
      int i = c * 64 + lane;
      unsigned long long kw = keepW[c];
      int kf = 0;
      if (i < PRE_NMS_N) kf = (int)((kw >> lane) & 1ull) & (fin[i] ? 1 : 0);
      unsigned long long m = __ballot(kf);
      if (kf) {
        int r = running + __popcll(m & ((1ull << lane) - 1ull));
        if (r < POST_NMS_N) {
          float4 b4 = sboxes[(size_t)n * PRE_NMS_N + i];
          float* o = out_rois + (size_t)(n * POST_NMS_N + r) * 4;
          o[0] = b4.x; o[1] = b4.y; o[2] = b4.z; o[3] = b4.w;
          out_valid[n * POST_NMS_N + r] = 1.0f;
        }
      }
      running += __popcll(m);
    }
    int keptTotal = running;
    if (keptTotal < POST_NMS_N) {
      int runN = 0;
      for (int c = 0; c < NWORD && keptTotal + runN < POST_NMS_N; ++c) {
        int i = c * 64 + lane;
        unsigned long long kw = keepW[c];
        int nf = 0;
        if (i < PRE_NMS_N) nf = !(((kw >> lane) & 1ull) && fin[i]);
        unsigned long long m = __ballot(nf);
        if (nf) {
          int r = keptTotal + runN + __popcll(m & ((1ull << lane) - 1ull));
          if (r < POST_NMS_N) {
            float* o = out_rois + (size_t)(n * POST_NMS_N + r) * 4;
            o[0] = 0.f; o[1] = 0.f; o[2] = 0.f; o[3] = 0.f;
            out_valid[n * POST_NMS_N + r] = 0.0f;
          }
        }
        runN += __popcll(m);
      }
    }
  }
}

extern "C" void kernel_launch(void* const* d_in, const int* in_sizes, int n_in,
                              void* d_out, int out_size, void* d_ws, size_t ws_size,
                              hipStream_t stream) {
  const float* x  = (const float*)d_in[0];
  const float* W1 = (const float*)d_in[1];
  const float* b1 = (const float*)d_in[2];
  const float* Ws = (const float*)d_in[3];
  const float* bs = (const float*)d_in[4];
  const float* Wl = (const float*)d_in[5];
  const float* bl = (const float*)d_in[6];
  const int* ihp  = (const int*)d_in[7];
  const int* iwp  = (const int*)d_in[8];

  float* out = (float*)d_out;
  float* o_locs   = out;
  float* o_scores = out + OFF_SCORES;
  float* o_rois   = out + OFF_ROIS;
  float* o_valid  = out + OFF_VALID;
  float* o_anch   = out + OFF_ANCH;

  char* ws = (char*)d_ws;
  const size_t OFF_WTH = 0;                  // 4,718,592
  const size_t OFF_WTL = 4718592;            // 4,718,592
  const size_t OFF_FG  = 9437184;            // 2,359,296
  const size_t OFF_DYN = 11796480;           // xh 4,460,544 | xl 4,460,544 | h 8,388,608

  _Float16* wth = (_Float16*)(ws + OFF_WTH);
  _Float16* wtl = (_Float16*)(ws + OFF_WTL);
  float* fg     = (float*)(ws + OFF_FG);
  _Float16* xh  = (_Float16*)(ws + OFF_DYN);
  _Float16* xl  = (_Float16*)(ws + OFF_DYN + 4460544);
  float* h      = (float*)(ws + OFF_DYN + 8921088);

  float4* boxes            = (float4*)(ws + OFF_DYN);
  unsigned long long* keys = (unsigned long long*)(ws + OFF_DYN + 2359296);
  float4* sboxes           = (float4*)(ws + OFF_DYN + 3538944);
  unsigned int* sfin       = (unsigned int*)(ws + OFF_DYN + 3730944);
  unsigned long long* mask = (unsigned long long*)(ws + OFF_DYN + 3778944);

  k0w_convert<<<dim3(9, 16), 256, 0, stream>>>(W1, wth, wtl);

  for (int img = 0; img < N_IMG; ++img) {
    k0x_convert<<<dim3(69, 8), 256, 0, stream>>>(x, xh, xl, img);
    k1_gemm<<<dim3(32, 8), 256, 0, stream>>>(xh, xl, wth, wtl, b1, h);
    k2_heads<<<dim3(64), 256, 0, stream>>>(h, Wl, bl, Ws, bs,
                                           o_locs, o_scores, fg, img);
  }

  k3_decode<<<(N_IMG * NANCH + 255) / 256, 256, 0, stream>>>(o_locs, fg, ihp, iwp,
                                                             o_anch, boxes, keys);
  k4_select<<<4, 1024, 0, stream>>>(keys, boxes, sboxes, sfin);
  k5_mask<<<dim3(NWORD, 4), 256, 0, stream>>>(sboxes, mask);
  k6_nms<<<4, 256, 0, stream>>>(mask, sboxes, sfin, o_rois, o_valid);
}

// Round 7
// 1573.129 us; speedup vs baseline: 1.5651x; 1.5651x over previous
//
#include <hip/hip_runtime.h>
#include <hip/hip_bf16.h>
#include <math.h>

#define N_IMG 4
#define CIN 512
#define NANCH 36864          // 64*64*9
#define PRE_NMS_N 3000
#define POST_NMS_N 300
#define NWORD 47             // ceil(3000/64)

// out layout (floats)
#define OFF_SCORES 589824
#define OFF_ROIS   884736
#define OFF_VALID  889536
#define OFF_ANCH   890736

typedef _Float16 f16x8 __attribute__((ext_vector_type(8)));
typedef float f32x4 __attribute__((ext_vector_type(4)));

__device__ __forceinline__ int swz(int p) { return (p + (p >> 2)) & 3; }

__device__ __forceinline__ unsigned long long rdlane64(unsigned long long v, int l) {
  unsigned int lo = (unsigned int)__builtin_amdgcn_readlane((int)(unsigned int)v, l);
  unsigned int hi = (unsigned int)__builtin_amdgcn_readlane((int)(unsigned int)(v >> 32), l);
  return (((unsigned long long)hi) << 32) | lo;
}

// ---------------- K0w: W1 [co][ci][tap] -> Wt_{h,l}[tap][co][ci], scaled x64 ----------
__global__ __launch_bounds__(256) void k0w_convert(
    const float* __restrict__ W1, _Float16* __restrict__ wth, _Float16* __restrict__ wtl) {
  const int tap = blockIdx.x, co0 = blockIdx.y * 32;
  for (int idx = threadIdx.x; idx < 32 * 512; idx += 256) {
    int col = idx >> 9, ci = idx & 511;
    float v = W1[(size_t)(co0 + col) * 4608 + ci * 9 + tap] * 64.0f;
    _Float16 hi = (_Float16)v;
    float lo = v - (float)hi;
    size_t o = ((size_t)(tap * 512 + co0 + col) << 9) + ci;
    wth[o] = hi; wtl[o] = (_Float16)lo;
  }
}

// ---------------- K0x: x [ci][64x64] -> padded xh/xl [66*66][512] f16 split -----------
__global__ __launch_bounds__(256) void k0x_convert(
    const float* __restrict__ x, _Float16* __restrict__ xh, _Float16* __restrict__ xl,
    int img) {
  const int bx = blockIdx.x, ci0 = blockIdx.y * 64;
  const int tid = threadIdx.x;
  if (bx < 64) {
    __shared__ float t[64][65];
    const float* xp = x + ((size_t)img * 512 + ci0) * 4096 + bx * 64;
    for (int idx = tid; idx < 4096; idx += 256) {
      int ci_l = idx >> 6, col = idx & 63;
      t[ci_l][col] = xp[(size_t)ci_l * 4096 + col];
    }
    __syncthreads();
    for (int idx = tid; idx < 4096; idx += 256) {
      int col = idx >> 6, ci_l = idx & 63;
      float v = t[ci_l][col];
      _Float16 hi = (_Float16)v;
      float lo = v - (float)hi;
      size_t o = (((size_t)(bx + 1) * 66 + col + 1) << 9) + ci0 + ci_l;
      xh[o] = hi; xl[o] = (_Float16)lo;
    }
  } else {
    for (int tt = tid; tt < 52 * 64; tt += 256) {
      int pl = tt >> 6, ci_l = tt & 63;
      int p = (bx - 64) * 52 + pl;
      if (p < 260) {
        int pp;
        if (p < 66) pp = p;
        else if (p < 132) pp = 65 * 66 + (p - 66);
        else if (p < 196) pp = (p - 132 + 1) * 66;
        else pp = (p - 196 + 1) * 66 + 65;
        size_t o = ((size_t)pp << 9) + ci0 + ci_l;
        xh[o] = (_Float16)0.f; xl[o] = (_Float16)0.f;
      }
    }
  }
}

// ---------------- K1: conv3x3 MFMA implicit GEMM (R5-proven config) -------------------
// grid (8 co-groups, 32 px-tiles): XCD = id%8 = co -> per-XCD W slice 1.2MB L2-resident.
// cb-outer/tap-inner: per-block A window 68KB stays L2-hot across the 9 taps.
// dist-1 prefetch, LDS-write AFTER MFMA: vmcnt wait overlaps compute.
__global__ __launch_bounds__(256) void k1_gemm(
    const _Float16* __restrict__ xh, const _Float16* __restrict__ xl,
    const _Float16* __restrict__ wth, const _Float16* __restrict__ wtl,
    const float* __restrict__ b1, float* __restrict__ h_out) {
  const int tid = threadIdx.x;
  const int co0 = blockIdx.x * 64;
  const int px0 = blockIdx.y * 128;
  const int y0 = px0 >> 6;

  __shared__ __align__(16) _Float16 AsL[4][4096];
  __shared__ __align__(16) _Float16 BsL[4][2048];

  const int lane = tid & 63, q = lane >> 4, lr = lane & 15;
  const int wid = tid >> 6, wm = wid & 1, wn = wid >> 1;

  int abase[2];
  #pragma unroll
  for (int it = 0; it < 2; ++it) {
    int s = it * 256 + tid;
    int pxl = s >> 2, cpos = s & 3;
    int c = cpos ^ swz(pxl);
    int row = pxl >> 6, xcol = pxl & 63;
    abase[it] = (((y0 + row) * 66 + xcol) << 9) + c * 8;
  }
  const int bcol = tid >> 2;
  const int bch = (tid & 3) ^ swz(bcol);
  const int bbase = ((co0 + bcol) << 9) + bch * 8;

  const int DD[9] = {0, 1, 2, 66, 67, 68, 132, 133, 134};

  f32x4 acc[4][2] = {};
  float4 rah[2], ral[2], rbh, rbl;

  #pragma unroll
  for (int it = 0; it < 2; ++it) {
    rah[it] = *(const float4*)(xh + abase[it]);
    ral[it] = *(const float4*)(xl + abase[it]);
  }
  rbh = *(const float4*)(wth + bbase);
  rbl = *(const float4*)(wtl + bbase);
  #pragma unroll
  for (int it = 0; it < 2; ++it) {
    *(float4*)&AsL[0][(it * 256 + tid) * 8] = rah[it];
    *(float4*)&AsL[1][(it * 256 + tid) * 8] = ral[it];
  }
  *(float4*)&BsL[0][tid * 8] = rbh;
  *(float4*)&BsL[1][tid * 8] = rbl;

  int tap = 0, cb = 0;   // tap fastest (cb-outer)
  for (int t = 0; t < 144; ++t) {
    __syncthreads();
    const int buf = t & 1;
    if (t < 143) {
      int tapn = tap + 1, cbn = cb;
      if (tapn == 9) { tapn = 0; cbn = cb + 1; }
      int ad = (DD[tapn] << 9) + cbn * 32;
      #pragma unroll
      for (int it = 0; it < 2; ++it) {
        rah[it] = *(const float4*)(xh + abase[it] + ad);
        ral[it] = *(const float4*)(xl + abase[it] + ad);
      }
      int bd = tapn * 262144 + cbn * 32;
      rbh = *(const float4*)(wth + bbase + bd);
      rbl = *(const float4*)(wtl + bbase + bd);
    }
    f16x8 ah[4], al[4], bh[2], bl[2];
    #pragma unroll
    for (int mi = 0; mi < 4; ++mi) {
      int pxl = wm * 64 + mi * 16 + lr;
      int cpr = q ^ swz(pxl);
      ah[mi] = *(const f16x8*)&AsL[buf * 2 + 0][pxl * 32 + cpr * 8];
      al[mi] = *(const f16x8*)&AsL[buf * 2 + 1][pxl * 32 + cpr * 8];
    }
    #pragma unroll
    for (int ni = 0; ni < 2; ++ni) {
      int col = wn * 32 + ni * 16 + lr;
      int cpr = q ^ swz(col);
      bh[ni] = *(const f16x8*)&BsL[buf * 2 + 0][col * 32 + cpr * 8];
      bl[ni] = *(const f16x8*)&BsL[buf * 2 + 1][col * 32 + cpr * 8];
    }
    #pragma unroll
    for (int mi = 0; mi < 4; ++mi)
      #pragma unroll
      for (int ni = 0; ni < 2; ++ni) {
        acc[mi][ni] = __builtin_amdgcn_mfma_f32_16x16x32_f16(ah[mi], bh[ni], acc[mi][ni], 0, 0, 0);
        acc[mi][ni] = __builtin_amdgcn_mfma_f32_16x16x32_f16(ah[mi], bl[ni], acc[mi][ni], 0, 0, 0);
        acc[mi][ni] = __builtin_amdgcn_mfma_f32_16x16x32_f16(al[mi], bh[ni], acc[mi][ni], 0, 0, 0);
      }
    if (t < 143) {
      int nb = (t + 1) & 1;
      #pragma unroll
      for (int it = 0; it < 2; ++it) {
        *(float4*)&AsL[nb * 2 + 0][(it * 256 + tid) * 8] = rah[it];
        *(float4*)&AsL[nb * 2 + 1][(it * 256 + tid) * 8] = ral[it];
      }
      *(float4*)&BsL[nb * 2 + 0][tid * 8] = rbh;
      *(float4*)&BsL[nb * 2 + 1][tid * 8] = rbl;
    }
    ++tap;
    if (tap == 9) { tap = 0; ++cb; }
  }

  float bb[2];
  #pragma unroll
  for (int ni = 0; ni < 2; ++ni) bb[ni] = b1[co0 + wn * 32 + ni * 16 + lr];
  #pragma unroll
  for (int mi = 0; mi < 4; ++mi)
    #pragma unroll
    for (int ni = 0; ni < 2; ++ni)
      #pragma unroll
      for (int rr = 0; rr < 4; ++rr) {
        int pxl = wm * 64 + mi * 16 + q * 4 + rr;
        int co = co0 + wn * 32 + ni * 16 + lr;
        float v = acc[mi][ni][rr] * 0.015625f + bb[ni];
        h_out[((size_t)(px0 + pxl) << 9) + co] = fmaxf(v, 0.f);
      }
}

// ---------------- K2: 1x1 heads + softmax-fg, K-split x4, 64 blocks/img ---------------
__global__ __launch_bounds__(256) void k2_heads(
    const float* __restrict__ h,
    const float* __restrict__ Wl, const float* __restrict__ bl,
    const float* __restrict__ Ws, const float* __restrict__ bs,
    float* __restrict__ rpn_locs, float* __restrict__ rpn_scores,
    float* __restrict__ fg, int img) {
  const int tid = threadIdx.x;
  const int px0 = blockIdx.x * 64;
  const int pxl = tid & 63, kq = tid >> 6;
  __shared__ float part[4][64][57];
  float acc[54];
  #pragma unroll
  for (int c = 0; c < 54; ++c) acc[c] = 0.f;
  const float* hp = h + ((size_t)(px0 + pxl) << 9) + kq * 128;
  for (int k = 0; k < 128; k += 4) {
    float4 a = *(const float4*)(hp + k);
    #pragma unroll
    for (int ch = 0; ch < 54; ++ch) {
      const float* wr = (ch < 36) ? (Wl + ch * 512) : (Ws + (ch - 36) * 512);
      float4 w = *(const float4*)(wr + kq * 128 + k);
      acc[ch] = fmaf(w.x, a.x, fmaf(w.y, a.y, fmaf(w.z, a.z, fmaf(w.w, a.w, acc[ch]))));
    }
  }
  #pragma unroll
  for (int ch = 0; ch < 54; ++ch) part[kq][pxl][ch] = acc[ch];
  __syncthreads();

  const int cq = kq;
  const int p = px0 + pxl;
  const size_t abase = (size_t)img * NANCH + (size_t)p * 9;
  if (cq < 3) {
    #pragma unroll
    for (int ai = 0; ai < 3; ++ai) {
      int a = cq * 3 + ai;
      float v[4];
      #pragma unroll
      for (int c = 0; c < 4; ++c) {
        int ch = a * 4 + c;
        v[c] = ((part[0][pxl][ch] + part[1][pxl][ch]) + part[2][pxl][ch]) +
               part[3][pxl][ch] + bl[ch];
      }
      float4 lv; lv.x = v[0]; lv.y = v[1]; lv.z = v[2]; lv.w = v[3];
      *(float4*)(rpn_locs + (abase + a) * 4) = lv;
    }
  } else {
    #pragma unroll
    for (int a = 0; a < 9; ++a) {
      int c0 = 36 + 2 * a, c1 = c0 + 1;
      float s0 = ((part[0][pxl][c0] + part[1][pxl][c0]) + part[2][pxl][c0]) +
                 part[3][pxl][c0] + bs[2 * a];
      float s1 = ((part[0][pxl][c1] + part[1][pxl][c1]) + part[2][pxl][c1]) +
                 part[3][pxl][c1] + bs[2 * a + 1];
      float2 sv; sv.x = s0; sv.y = s1;
      *(float2*)(rpn_scores + (abase + a) * 2) = sv;
      float m = fmaxf(s0, s1);
      float e0 = expf(s0 - m), e1 = expf(s1 - m);
      fg[abase + a] = e1 / (e0 + e1);
    }
  }
}

// ---------------- K3: anchors + decode + clip + key ----------------
__global__ void k3_decode(
    const float* __restrict__ locs, const float* __restrict__ fg,
    const int* __restrict__ ihp, const int* __restrict__ iwp,
    float* __restrict__ anchors_out, float4* __restrict__ boxes,
    unsigned long long* __restrict__ keys) {
  int gid = blockIdx.x * 256 + threadIdx.x;
  if (gid >= N_IMG * NANCH) return;
  int n = gid / NANCH, i = gid - n * NANCH;
  int p = i / 9, a = i - p * 9;
  int yy = p >> 6, xx = p & 63;
  int ri = a / 3, si = a - ri * 3;
  const float ratios[3] = {0.5f, 1.0f, 2.0f};
  const float scales[3] = {8.f, 16.f, 32.f};
  float hh = 16.f * scales[si] * sqrtf(ratios[ri]);
  float ww = 16.f * scales[si] * sqrtf(1.0f / ratios[ri]);
  float by1 = 8.f - hh * 0.5f, bx1 = 8.f - ww * 0.5f;
  float by2 = 8.f + hh * 0.5f, bx2 = 8.f + ww * 0.5f;
  float ay1 = yy * 16.f + by1, ax1 = xx * 16.f + bx1;
  float ay2 = yy * 16.f + by2, ax2 = xx * 16.f + bx2;
  if (n == 0) {
    float* ao = anchors_out + (size_t)i * 4;
    ao[0] = ay1; ao[1] = ax1; ao[2] = ay2; ao[3] = ax2;
  }
  const float* lp = locs + ((size_t)n * NANCH + i) * 4;
  float dy = lp[0], dx = lp[1], dh = lp[2], dw = lp[3];
  float ah = ay2 - ay1, aw = ax2 - ax1;
  float acy = ay1 + 0.5f * ah, acx = ax1 + 0.5f * aw;
  float cy = dy * ah + acy, cx = dx * aw + acx;
  float hb = expf(dh) * ah, wb = expf(dw) * aw;
  float imh = (float)ihp[0], imw = (float)iwp[0];
  float y1 = fminf(fmaxf(cy - 0.5f * hb, 0.f), imh);
  float x1 = fminf(fmaxf(cx - 0.5f * wb, 0.f), imw);
  float y2 = fminf(fmaxf(cy + 0.5f * hb, 0.f), imh);
  float x2 = fminf(fmaxf(cx + 0.5f * wb, 0.f), imw);
  bool valid = ((y2 - y1) >= 16.0f) && ((x2 - x1) >= 16.0f);
  float s = valid ? fg[(size_t)n * NANCH + i] : -__builtin_inff();
  boxes[(size_t)n * NANCH + i] = make_float4(y1, x1, y2, x2);
  unsigned int fb = __float_as_uint(s);
  unsigned int mono = (fb & 0x80000000u) ? ~fb : (fb | 0x80000000u);
  keys[(size_t)n * NANCH + i] =
      (((unsigned long long)mono) << 32) | (unsigned int)(~(unsigned int)i);
}

// ---------------- K4: per-image exact top-3000 (sorted desc) ----------------
__global__ __launch_bounds__(1024) void k4_select(
    const unsigned long long* __restrict__ keys, const float4* __restrict__ boxes,
    float4* __restrict__ sboxes, unsigned int* __restrict__ sfin) {
  const int n = blockIdx.x, tid = threadIdx.x;
  const unsigned long long* kk = keys + (size_t)n * NANCH;
  __shared__ unsigned int hist[2048];
  __shared__ unsigned int suf[2048];
  __shared__ unsigned long long sb[4096];
  __shared__ int selb;
  __shared__ unsigned int cnt;
  unsigned long long prefix = 0ull;
  int need = PRE_NMS_N;
  const int shifts[6] = {53, 42, 31, 20, 10, 0};
  const int widths[6] = {11, 11, 11, 11, 10, 10};
  for (int rd = 0; rd < 6; ++rd) {
    const int s = shifts[rd], w = widths[rd];
    const int hib = s + w;
    for (int b = tid; b < 2048; b += 1024) hist[b] = 0u;
    __syncthreads();
    for (int i = tid; i < NANCH; i += 1024) {
      unsigned long long key = kk[i];
      bool match = (hib >= 64) || (((key ^ prefix) >> hib) == 0ull);
      if (match)
        atomicAdd(&hist[(unsigned)((key >> s) & ((1u << w) - 1u))], 1u);
    }
    __syncthreads();
    for (int off = 1; off < 2048; off <<= 1) {
      for (int b = tid; b < 2048; b += 1024)
        suf[b] = hist[b] + ((b + off < 2048) ? hist[b + off] : 0u);
      __syncthreads();
      for (int b = tid; b < 2048; b += 1024) hist[b] = suf[b];
      __syncthreads();
    }
    const int nb = 1 << w;
    for (int b = tid; b < nb; b += 1024) {
      unsigned int sv = hist[b];
      unsigned int nxt = (b + 1 < 2048) ? hist[b + 1] : 0u;
      if (sv >= (unsigned)need && nxt < (unsigned)need) selb = b;
    }
    __syncthreads();
    int bstar = selb;
    unsigned int cgt = (bstar + 1 < 2048) ? hist[bstar + 1] : 0u;
    need -= (int)cgt;
    prefix |= ((unsigned long long)bstar) << s;
    __syncthreads();
  }
  if (tid == 0) cnt = 0u;
  __syncthreads();
  for (int i = tid; i < NANCH; i += 1024) {
    unsigned long long key = kk[i];
    if (key >= prefix) {
      unsigned int pos = atomicAdd(&cnt, 1u);
      if (pos < 4096u) sb[pos] = ~key;
    }
  }
  __syncthreads();
  unsigned int c0 = cnt;
  for (int i = tid; i < 4096; i += 1024)
    if (i >= (int)c0) sb[i] = 0xFFFFFFFFFFFFFFFFull;
  __syncthreads();
  for (int k2 = 2; k2 <= 4096; k2 <<= 1) {
    for (int j = k2 >> 1; j > 0; j >>= 1) {
      for (int t = tid; t < 2048; t += 1024) {
        int i = ((t & ~(j - 1)) << 1) | (t & (j - 1));
        int pp = i + j;
        bool up = ((i & k2) == 0);
        unsigned long long va = sb[i], vb = sb[pp];
        bool sw = up ? (va > vb) : (va < vb);
        if (sw) { sb[i] = vb; sb[pp] = va; }
      }
      __syncthreads();
    }
  }
  const float4* bx = boxes + (size_t)n * NANCH;
  for (int r = tid; r < PRE_NMS_N; r += 1024) {
    unsigned long long key = ~sb[r];
    unsigned int idx = ~((unsigned int)(key & 0xFFFFFFFFull));
    sboxes[(size_t)n * PRE_NMS_N + r] = bx[idx];
    unsigned int hi32 = (unsigned int)(key >> 32);
    sfin[n * PRE_NMS_N + r] = (hi32 > 0x007FFFFFu) ? 1u : 0u;
  }
}

// ---------------- K5: suppression bitmask (wave-per-item, ballot, triangle) -----------
__global__ __launch_bounds__(256) void k5_mask(
    const float4* __restrict__ sboxes, unsigned long long* __restrict__ mask) {
  const int c = blockIdx.x, n = blockIdx.y;
  __shared__ float sy1[3008], sx1[3008], sy2[3008], sx2[3008], sar[3008];
  const int tid = threadIdx.x;
  for (int i = tid; i < PRE_NMS_N; i += 256) {
    float4 b = sboxes[(size_t)n * PRE_NMS_N + i];
    sy1[i] = b.x; sx1[i] = b.y; sy2[i] = b.z; sx2[i] = b.w;
    sar[i] = (b.z - b.x) * (b.w - b.y);
  }
  for (int i = PRE_NMS_N + tid; i < 3008; i += 256) {
    sy1[i] = 0.f; sx1[i] = 0.f; sy2[i] = 0.f; sx2[i] = 0.f; sar[i] = 0.f;
  }
  __syncthreads();
  const int lane = tid & 63, wv = tid >> 6;
  const int nwd = NWORD - c;
  const int nitems = 64 * nwd;
  for (int it = wv; it < nitems; it += 4) {
    int il = it & 63, wd = c + (it >> 6);
    int i = c * 64 + il;
    if (i >= PRE_NMS_N) continue;
    float biy1 = sy1[i], bix1 = sx1[i], biy2 = sy2[i], bix2 = sx2[i], bia = sar[i];
    int j = wd * 64 + lane;
    float y1 = fmaxf(biy1, sy1[j]), x1 = fmaxf(bix1, sx1[j]);
    float y2 = fminf(biy2, sy2[j]), x2 = fminf(bix2, sx2[j]);
    float inter = fmaxf(y2 - y1, 0.f) * fmaxf(x2 - x1, 0.f);
    float uni = bia + sar[j] - inter;
    float iou = (uni > 0.f) ? inter / uni : 0.f;
    bool pr = (j < PRE_NMS_N) && (iou > 0.7f);
    unsigned long long bits = __ballot(pr);
    if (lane == 0)
      mask[((size_t)n * PRE_NMS_N + i) * NWORD + wd] = bits;
  }
}

// ---------------- K6: chunked greedy NMS, LDS-staged slabs, 256 thr, wave0 serial -----
__global__ __launch_bounds__(256) void k6_nms(
    const unsigned long long* __restrict__ mask, const float4* __restrict__ sboxes,
    const unsigned int* __restrict__ sfin,
    float* __restrict__ out_rois, float* __restrict__ out_valid) {
  const int n = blockIdx.x, tid = threadIdx.x;
  const int lane = tid & 63;
  const unsigned long long* M = mask + (size_t)n * PRE_NMS_N * NWORD;
  __shared__ unsigned long long rows[2][64][NWORD];
  __shared__ unsigned long long keepW[NWORD];

  #pragma unroll
  for (int j = 0; j < 12; ++j) {
    int idx = j * 256 + tid;
    if (idx < 64 * NWORD) {
      int row = idx / NWORD, w = idx - row * NWORD;
      rows[0][row][w] = M[(size_t)row * NWORD + w];
    }
  }
  __syncthreads();

  unsigned long long Rw = 0ull;
  for (int c = 0; c < NWORD; ++c) {
    const int buf = c & 1;
    const int i0 = c * 64;
    const int nIt = (c == NWORD - 1) ? (PRE_NMS_N - i0) : 64;
    unsigned long long pf[12];
    const bool hasNext = (c + 1 < NWORD);
    if (hasNext) {
      const int i1 = (c + 1) * 64;
      #pragma unroll
      for (int j = 0; j < 12; ++j) {
        int idx = j * 256 + tid;
        if (idx < 64 * NWORD) {
          int row = idx / NWORD, w = idx - row * NWORD;
          int gi = i1 + row;
          pf[j] = (gi < PRE_NMS_N) ? M[(size_t)gi * NWORD + w] : 0ull;
        }
      }
    }
    if (tid < 64) {
      unsigned long long Dcur = rows[buf][lane][c];
      unsigned long long rem = rdlane64(Rw, c);
      unsigned long long und = ~rem;
      if (nIt < 64) und &= ((1ull << nIt) - 1ull);
      unsigned long long kept = 0ull;
      while (und) {
        int b = __builtin_ctzll(und);
        kept |= (1ull << b);
        unsigned long long db = rdlane64(Dcur, b);
        und &= ~db;
        und &= ~(1ull << b);
      }
      if (lane == 0) keepW[c] = kept;
      const bool upd = (lane > c) && (lane < NWORD);
      unsigned long long kk = kept;
      while (kk) {
        int b0 = __builtin_ctzll(kk); kk &= kk - 1ull;
        int b1 = b0, b2 = b0, b3 = b0;
        if (kk) { b1 = __builtin_ctzll(kk); kk &= kk - 1ull; }
        if (kk) { b2 = __builtin_ctzll(kk); kk &= kk - 1ull; }
        if (kk) { b3 = __builtin_ctzll(kk); kk &= kk - 1ull; }
        if (upd) {
          unsigned long long v0 = rows[buf][b0][lane];
          unsigned long long v1 = rows[buf][b1][lane];
          unsigned long long v2 = rows[buf][b2][lane];
          unsigned long long v3 = rows[buf][b3][lane];
          Rw |= (v0 | v1) | (v2 | v3);
        }
      }
    }
    if (hasNext) {
      #pragma unroll
      for (int j = 0; j < 12; ++j) {
        int idx = j * 256 + tid;
        if (idx < 64 * NWORD) {
          int row = idx / NWORD, w = idx - row * NWORD;
          rows[buf ^ 1][row][w] = pf[j];
        }
      }
    }
    __syncthreads();
  }

  if (tid < 64) {
    const unsigned int* fin = sfin + n * PRE_NMS_N;
    int running = 0;
    for (int c = 0; c < NWORD; ++c) {
      int i = c * 64 + lane;
      unsigned long long kw = keepW[c];
      int kf = 0;
      if (i < PRE_NMS_N) kf = (int)((kw >> lane) & 1ull) & (fin[i] ? 1 : 0);
      unsigned long long m = __ballot(kf);
      if (kf) {
        int r = running + __popcll(m & ((1ull << lane) - 1ull));
        if (r < POST_NMS_N) {
          float4 b4 = sboxes[(size_t)n * PRE_NMS_N + i];
          float* o = out_rois + (size_t)(n * POST_NMS_N + r) * 4;
          o[0] = b4.x; o[1] = b4.y; o[2] = b4.z; o[3] = b4.w;
          out_valid[n * POST_NMS_N + r] = 1.0f;
        }
      }
      running += __popcll(m);
    }
    int keptTotal = running;
    if (keptTotal < POST_NMS_N) {
      int runN = 0;
      for (int c = 0; c < NWORD && keptTotal + runN < POST_NMS_N; ++c) {
        int i = c * 64 + lane;
        unsigned long long kw = keepW[c];
        int nf = 0;
        if (i < PRE_NMS_N) nf = !(((kw >> lane) & 1ull) && fin[i]);
        unsigned long long m = __ballot(nf);
        if (nf) {
          int r = keptTotal + runN + __popcll(m & ((1ull << lane) - 1ull));
          if (r < POST_NMS_N) {
            float* o = out_rois + (size_t)(n * POST_NMS_N + r) * 4;
            o[0] = 0.f; o[1] = 0.f; o[2] = 0.f; o[3] = 0.f;
            out_valid[n * POST_NMS_N + r] = 0.0f;
          }
        }
        runN += __popcll(m);
      }
    }
  }
}

extern "C" void kernel_launch(void* const* d_in, const int* in_sizes, int n_in,
                              void* d_out, int out_size, void* d_ws, size_t ws_size,
                              hipStream_t stream) {
  const float* x  = (const float*)d_in[0];
  const float* W1 = (const float*)d_in[1];
  const float* b1 = (const float*)d_in[2];
  const float* Ws = (const float*)d_in[3];
  const float* bs = (const float*)d_in[4];
  const float* Wl = (const float*)d_in[5];
  const float* bl = (const float*)d_in[6];
  const int* ihp  = (const int*)d_in[7];
  const int* iwp  = (const int*)d_in[8];

  float* out = (float*)d_out;
  float* o_locs   = out;
  float* o_scores = out + OFF_SCORES;
  float* o_rois   = out + OFF_ROIS;
  float* o_valid  = out + OFF_VALID;
  float* o_anch   = out + OFF_ANCH;

  char* ws = (char*)d_ws;
  const size_t OFF_WTH = 0;                  // 4,718,592
  const size_t OFF_WTL = 4718592;            // 4,718,592
  const size_t OFF_FG  = 9437184;            // 2,359,296
  const size_t OFF_DYN = 11796480;           // xh 4,460,544 | xl 4,460,544 | h 8,388,608

  _Float16* wth = (_Float16*)(ws + OFF_WTH);
  _Float16* wtl = (_Float16*)(ws + OFF_WTL);
  float* fg     = (float*)(ws + OFF_FG);
  _Float16* xh  = (_Float16*)(ws + OFF_DYN);
  _Float16* xl  = (_Float16*)(ws + OFF_DYN + 4460544);
  float* h      = (float*)(ws + OFF_DYN + 8921088);

  float4* boxes            = (float4*)(ws + OFF_DYN);
  unsigned long long* keys = (unsigned long long*)(ws + OFF_DYN + 2359296);
  float4* sboxes           = (float4*)(ws + OFF_DYN + 3538944);
  unsigned int* sfin       = (unsigned int*)(ws + OFF_DYN + 3730944);
  unsigned long long* mask = (unsigned long long*)(ws + OFF_DYN + 3778944);

  k0w_convert<<<dim3(9, 16), 256, 0, stream>>>(W1, wth, wtl);

  for (int img = 0; img < N_IMG; ++img) {
    k0x_convert<<<dim3(69, 8), 256, 0, stream>>>(x, xh, xl, img);
    k1_gemm<<<dim3(8, 32), 256, 0, stream>>>(xh, xl, wth, wtl, b1, h);
    k2_heads<<<dim3(64), 256, 0, stream>>>(h, Wl, bl, Ws, bs,
                                           o_locs, o_scores, fg, img);
  }

  k3_decode<<<(N_IMG * NANCH + 255) / 256, 256, 0, stream>>>(o_locs, fg, ihp, iwp,
                                                             o_anch, boxes, keys);
  k4_select<<<4, 1024, 0, stream>>>(keys, boxes, sboxes, sfin);
  k5_mask<<<dim3(NWORD, 4), 256, 0, stream>>>(sboxes, mask);
  k6_nms<<<4, 256, 0, stream>>>(mask, sboxes, sfin, o_rois, o_valid);
}

// Round 8
// 864.359 us; speedup vs baseline: 2.8486x; 1.8200x over previous
//
#include <hip/hip_runtime.h>
#include <hip/hip_bf16.h>
#include <math.h>

#define N_IMG 4
#define CIN 512
#define NANCH 36864          // 64*64*9
#define PRE_NMS_N 3000
#define POST_NMS_N 300
#define NWORD 47             // ceil(3000/64)
#define NPAIR 1128           // NWORD*(NWORD+1)/2
#define PPX 4356             // 66*66 padded pixels

// out layout (floats)
#define OFF_SCORES 589824
#define OFF_ROIS   884736
#define OFF_VALID  889536
#define OFF_ANCH   890736

typedef _Float16 f16x8 __attribute__((ext_vector_type(8)));
typedef float f32x4 __attribute__((ext_vector_type(4)));

__device__ __forceinline__ int swz(int p) { return (p + (p >> 2)) & 3; }

__device__ __forceinline__ unsigned long long rdlane64(unsigned long long v, int l) {
  unsigned int lo = (unsigned int)__builtin_amdgcn_readlane((int)(unsigned int)v, l);
  unsigned int hi = (unsigned int)__builtin_amdgcn_readlane((int)(unsigned int)(v >> 32), l);
  return (((unsigned long long)hi) << 32) | lo;
}

// ---------------- K0w: W1 [co][ci][tap] -> Wt_{h,l}[tap][co][ci], scaled x64 ----------
__global__ __launch_bounds__(256) void k0w_convert(
    const float* __restrict__ W1, _Float16* __restrict__ wth, _Float16* __restrict__ wtl) {
  const int tap = blockIdx.x, co0 = blockIdx.y * 32;
  for (int idx = threadIdx.x; idx < 32 * 512; idx += 256) {
    int col = idx >> 9, ci = idx & 511;
    float v = W1[(size_t)(co0 + col) * 4608 + ci * 9 + tap] * 64.0f;
    _Float16 hi = (_Float16)v;
    float lo = v - (float)hi;
    size_t o = ((size_t)(tap * 512 + co0 + col) << 9) + ci;
    wth[o] = hi; wtl[o] = (_Float16)lo;
  }
}

// ---------------- K0x: x [ci][64x64] -> padded xh/xl [img_l][66*66][512] f16 split ----
__global__ __launch_bounds__(256) void k0x_convert(
    const float* __restrict__ x, _Float16* __restrict__ xh, _Float16* __restrict__ xl,
    int img0) {
  const int bx = blockIdx.x, ci0 = blockIdx.y * 64;
  const int img_l = blockIdx.z;
  const int img = img0 + img_l;
  const size_t sbase = (size_t)img_l * PPX;
  const int tid = threadIdx.x;
  if (bx < 64) {
    __shared__ float t[64][65];
    const float* xp = x + ((size_t)img * 512 + ci0) * 4096 + bx * 64;
    for (int idx = tid; idx < 4096; idx += 256) {
      int ci_l = idx >> 6, col = idx & 63;
      t[ci_l][col] = xp[(size_t)ci_l * 4096 + col];
    }
    __syncthreads();
    for (int idx = tid; idx < 4096; idx += 256) {
      int col = idx >> 6, ci_l = idx & 63;
      float v = t[ci_l][col];
      _Float16 hi = (_Float16)v;
      float lo = v - (float)hi;
      size_t o = ((sbase + (size_t)(bx + 1) * 66 + col + 1) << 9) + ci0 + ci_l;
      xh[o] = hi; xl[o] = (_Float16)lo;
    }
  } else {
    for (int tt = tid; tt < 52 * 64; tt += 256) {
      int pl = tt >> 6, ci_l = tt & 63;
      int p = (bx - 64) * 52 + pl;
      if (p < 260) {
        int pp;
        if (p < 66) pp = p;
        else if (p < 132) pp = 65 * 66 + (p - 66);
        else if (p < 196) pp = (p - 132 + 1) * 66;
        else pp = (p - 196 + 1) * 66 + 65;
        size_t o = ((sbase + pp) << 9) + ci0 + ci_l;
        xh[o] = (_Float16)0.f; xl[o] = (_Float16)0.f;
      }
    }
  }
}

// ---------------- K1: conv3x3 MFMA implicit GEMM (R5-proven structure, multi-img) -----
// grid (8 co-groups, nipp*32 px-tiles): id%8 = co -> per-XCD W slice 1.2MB L2-resident.
// cb-outer/tap-inner; dist-1 prefetch; LDS-write AFTER MFMA (vmcnt overlaps compute).
__global__ __launch_bounds__(256) void k1_gemm(
    const _Float16* __restrict__ xh, const _Float16* __restrict__ xl,
    const _Float16* __restrict__ wth, const _Float16* __restrict__ wtl,
    const float* __restrict__ b1, float* __restrict__ h_out) {
  const int tid = threadIdx.x;
  const int co0 = blockIdx.x * 64;
  const int px0 = blockIdx.y * 128;          // linear px across nipp images
  const int img_l = px0 >> 12;
  const int y0 = (px0 & 4095) >> 6;

  __shared__ __align__(16) _Float16 AsL[4][4096];
  __shared__ __align__(16) _Float16 BsL[4][2048];

  const int lane = tid & 63, q = lane >> 4, lr = lane & 15;
  const int wid = tid >> 6, wm = wid & 1, wn = wid >> 1;

  int abase[2];
  #pragma unroll
  for (int it = 0; it < 2; ++it) {
    int s = it * 256 + tid;
    int pxl = s >> 2, cpos = s & 3;
    int c = cpos ^ swz(pxl);
    int row = pxl >> 6, xcol = pxl & 63;
    abase[it] = ((img_l * PPX + (y0 + row) * 66 + xcol) << 9) + c * 8;
  }
  const int bcol = tid >> 2;
  const int bch = (tid & 3) ^ swz(bcol);
  const int bbase = ((co0 + bcol) << 9) + bch * 8;

  const int DD[9] = {0, 1, 2, 66, 67, 68, 132, 133, 134};

  f32x4 acc[4][2] = {};
  float4 rah[2], ral[2], rbh, rbl;

  #pragma unroll
  for (int it = 0; it < 2; ++it) {
    rah[it] = *(const float4*)(xh + abase[it]);
    ral[it] = *(const float4*)(xl + abase[it]);
  }
  rbh = *(const float4*)(wth + bbase);
  rbl = *(const float4*)(wtl + bbase);
  #pragma unroll
  for (int it = 0; it < 2; ++it) {
    *(float4*)&AsL[0][(it * 256 + tid) * 8] = rah[it];
    *(float4*)&AsL[1][(it * 256 + tid) * 8] = ral[it];
  }
  *(float4*)&BsL[0][tid * 8] = rbh;
  *(float4*)&BsL[1][tid * 8] = rbl;

  int tap = 0, cb = 0;   // tap fastest (cb-outer)
  for (int t = 0; t < 144; ++t) {
    __syncthreads();
    const int buf = t & 1;
    if (t < 143) {
      int tapn = tap + 1, cbn = cb;
      if (tapn == 9) { tapn = 0; cbn = cb + 1; }
      int ad = (DD[tapn] << 9) + cbn * 32;
      #pragma unroll
      for (int it = 0; it < 2; ++it) {
        rah[it] = *(const float4*)(xh + abase[it] + ad);
        ral[it] = *(const float4*)(xl + abase[it] + ad);
      }
      int bd = tapn * 262144 + cbn * 32;
      rbh = *(const float4*)(wth + bbase + bd);
      rbl = *(const float4*)(wtl + bbase + bd);
    }
    f16x8 ah[4], al[4], bh[2], bl[2];
    #pragma unroll
    for (int mi = 0; mi < 4; ++mi) {
      int pxl = wm * 64 + mi * 16 + lr;
      int cpr = q ^ swz(pxl);
      ah[mi] = *(const f16x8*)&AsL[buf * 2 + 0][pxl * 32 + cpr * 8];
      al[mi] = *(const f16x8*)&AsL[buf * 2 + 1][pxl * 32 + cpr * 8];
    }
    #pragma unroll
    for (int ni = 0; ni < 2; ++ni) {
      int col = wn * 32 + ni * 16 + lr;
      int cpr = q ^ swz(col);
      bh[ni] = *(const f16x8*)&BsL[buf * 2 + 0][col * 32 + cpr * 8];
      bl[ni] = *(const f16x8*)&BsL[buf * 2 + 1][col * 32 + cpr * 8];
    }
    #pragma unroll
    for (int mi = 0; mi < 4; ++mi)
      #pragma unroll
      for (int ni = 0; ni < 2; ++ni) {
        acc[mi][ni] = __builtin_amdgcn_mfma_f32_16x16x32_f16(ah[mi], bh[ni], acc[mi][ni], 0, 0, 0);
        acc[mi][ni] = __builtin_amdgcn_mfma_f32_16x16x32_f16(ah[mi], bl[ni], acc[mi][ni], 0, 0, 0);
        acc[mi][ni] = __builtin_amdgcn_mfma_f32_16x16x32_f16(al[mi], bh[ni], acc[mi][ni], 0, 0, 0);
      }
    if (t < 143) {
      int nb = (t + 1) & 1;
      #pragma unroll
      for (int it = 0; it < 2; ++it) {
        *(float4*)&AsL[nb * 2 + 0][(it * 256 + tid) * 8] = rah[it];
        *(float4*)&AsL[nb * 2 + 1][(it * 256 + tid) * 8] = ral[it];
      }
      *(float4*)&BsL[nb * 2 + 0][tid * 8] = rbh;
      *(float4*)&BsL[nb * 2 + 1][tid * 8] = rbl;
    }
    ++tap;
    if (tap == 9) { tap = 0; ++cb; }
  }

  float bb[2];
  #pragma unroll
  for (int ni = 0; ni < 2; ++ni) bb[ni] = b1[co0 + wn * 32 + ni * 16 + lr];
  #pragma unroll
  for (int mi = 0; mi < 4; ++mi)
    #pragma unroll
    for (int ni = 0; ni < 2; ++ni)
      #pragma unroll
      for (int rr = 0; rr < 4; ++rr) {
        int pxl = wm * 64 + mi * 16 + q * 4 + rr;
        int co = co0 + wn * 32 + ni * 16 + lr;
        float v = acc[mi][ni][rr] * 0.015625f + bb[ni];
        h_out[((size_t)(px0 + pxl) << 9) + co] = fmaxf(v, 0.f);
      }
}

// ---------------- K2: 1x1 heads + softmax-fg, K-split x4 (multi-img linear px) --------
__global__ __launch_bounds__(256) void k2_heads(
    const float* __restrict__ h,
    const float* __restrict__ Wl, const float* __restrict__ bl,
    const float* __restrict__ Ws, const float* __restrict__ bs,
    float* __restrict__ rpn_locs, float* __restrict__ rpn_scores,
    float* __restrict__ fg, int img0) {
  const int tid = threadIdx.x;
  const int px0 = blockIdx.x * 64;           // linear px across nipp images
  const int pxl = tid & 63, kq = tid >> 6;
  __shared__ float part[4][64][57];
  float acc[54];
  #pragma unroll
  for (int c = 0; c < 54; ++c) acc[c] = 0.f;
  const float* hp = h + ((size_t)(px0 + pxl) << 9) + kq * 128;
  for (int k = 0; k < 128; k += 4) {
    float4 a = *(const float4*)(hp + k);
    #pragma unroll
    for (int ch = 0; ch < 54; ++ch) {
      const float* wr = (ch < 36) ? (Wl + ch * 512) : (Ws + (ch - 36) * 512);
      float4 w = *(const float4*)(wr + kq * 128 + k);
      acc[ch] = fmaf(w.x, a.x, fmaf(w.y, a.y, fmaf(w.z, a.z, fmaf(w.w, a.w, acc[ch]))));
    }
  }
  #pragma unroll
  for (int ch = 0; ch < 54; ++ch) part[kq][pxl][ch] = acc[ch];
  __syncthreads();

  const int cq = kq;
  const int p = px0 + pxl;
  const int img = img0 + (p >> 12);
  const int p_loc = p & 4095;
  const size_t abase = (size_t)img * NANCH + (size_t)p_loc * 9;
  if (cq < 3) {
    #pragma unroll
    for (int ai = 0; ai < 3; ++ai) {
      int a = cq * 3 + ai;
      float v[4];
      #pragma unroll
      for (int c = 0; c < 4; ++c) {
        int ch = a * 4 + c;
        v[c] = ((part[0][pxl][ch] + part[1][pxl][ch]) + part[2][pxl][ch]) +
               part[3][pxl][ch] + bl[ch];
      }
      float4 lv; lv.x = v[0]; lv.y = v[1]; lv.z = v[2]; lv.w = v[3];
      *(float4*)(rpn_locs + (abase + a) * 4) = lv;
    }
  } else {
    #pragma unroll
    for (int a = 0; a < 9; ++a) {
      int c0 = 36 + 2 * a, c1 = c0 + 1;
      float s0 = ((part[0][pxl][c0] + part[1][pxl][c0]) + part[2][pxl][c0]) +
                 part[3][pxl][c0] + bs[2 * a];
      float s1 = ((part[0][pxl][c1] + part[1][pxl][c1]) + part[2][pxl][c1]) +
                 part[3][pxl][c1] + bs[2 * a + 1];
      float2 sv; sv.x = s0; sv.y = s1;
      *(float2*)(rpn_scores + (abase + a) * 2) = sv;
      float m = fmaxf(s0, s1);
      float e0 = expf(s0 - m), e1 = expf(s1 - m);
      fg[abase + a] = e1 / (e0 + e1);
    }
  }
}

// ---------------- K3: anchors + decode + clip + key ----------------
__global__ void k3_decode(
    const float* __restrict__ locs, const float* __restrict__ fg,
    const int* __restrict__ ihp, const int* __restrict__ iwp,
    float* __restrict__ anchors_out, float4* __restrict__ boxes,
    unsigned long long* __restrict__ keys) {
  int gid = blockIdx.x * 256 + threadIdx.x;
  if (gid >= N_IMG * NANCH) return;
  int n = gid / NANCH, i = gid - n * NANCH;
  int p = i / 9, a = i - p * 9;
  int yy = p >> 6, xx = p & 63;
  int ri = a / 3, si = a - ri * 3;
  const float ratios[3] = {0.5f, 1.0f, 2.0f};
  const float scales[3] = {8.f, 16.f, 32.f};
  float hh = 16.f * scales[si] * sqrtf(ratios[ri]);
  float ww = 16.f * scales[si] * sqrtf(1.0f / ratios[ri]);
  float by1 = 8.f - hh * 0.5f, bx1 = 8.f - ww * 0.5f;
  float by2 = 8.f + hh * 0.5f, bx2 = 8.f + ww * 0.5f;
  float ay1 = yy * 16.f + by1, ax1 = xx * 16.f + bx1;
  float ay2 = yy * 16.f + by2, ax2 = xx * 16.f + bx2;
  if (n == 0) {
    float* ao = anchors_out + (size_t)i * 4;
    ao[0] = ay1; ao[1] = ax1; ao[2] = ay2; ao[3] = ax2;
  }
  const float* lp = locs + ((size_t)n * NANCH + i) * 4;
  float dy = lp[0], dx = lp[1], dh = lp[2], dw = lp[3];
  float ah = ay2 - ay1, aw = ax2 - ax1;
  float acy = ay1 + 0.5f * ah, acx = ax1 + 0.5f * aw;
  float cy = dy * ah + acy, cx = dx * aw + acx;
  float hb = expf(dh) * ah, wb = expf(dw) * aw;
  float imh = (float)ihp[0], imw = (float)iwp[0];
  float y1 = fminf(fmaxf(cy - 0.5f * hb, 0.f), imh);
  float x1 = fminf(fmaxf(cx - 0.5f * wb, 0.f), imw);
  float y2 = fminf(fmaxf(cy + 0.5f * hb, 0.f), imh);
  float x2 = fminf(fmaxf(cx + 0.5f * wb, 0.f), imw);
  bool valid = ((y2 - y1) >= 16.0f) && ((x2 - x1) >= 16.0f);
  float s = valid ? fg[(size_t)n * NANCH + i] : -__builtin_inff();
  boxes[(size_t)n * NANCH + i] = make_float4(y1, x1, y2, x2);
  unsigned int fb = __float_as_uint(s);
  unsigned int mono = (fb & 0x80000000u) ? ~fb : (fb | 0x80000000u);
  keys[(size_t)n * NANCH + i] =
      (((unsigned long long)mono) << 32) | (unsigned int)(~(unsigned int)i);
}

// ---------------- K4: per-image exact top-3000 (sorted desc) ----------------
__global__ __launch_bounds__(1024) void k4_select(
    const unsigned long long* __restrict__ keys, const float4* __restrict__ boxes,
    float4* __restrict__ sboxes, unsigned int* __restrict__ sfin) {
  const int n = blockIdx.x, tid = threadIdx.x;
  const unsigned long long* kk = keys + (size_t)n * NANCH;
  __shared__ unsigned int hist[2048];
  __shared__ unsigned int suf[2048];
  __shared__ unsigned long long sb[4096];
  __shared__ int selb;
  __shared__ unsigned int cnt;
  unsigned long long prefix = 0ull;
  int need = PRE_NMS_N;
  const int shifts[6] = {53, 42, 31, 20, 10, 0};
  const int widths[6] = {11, 11, 11, 11, 10, 10};
  for (int rd = 0; rd < 6; ++rd) {
    const int s = shifts[rd], w = widths[rd];
    const int hib = s + w;
    for (int b = tid; b < 2048; b += 1024) hist[b] = 0u;
    __syncthreads();
    for (int i = tid; i < NANCH; i += 1024) {
      unsigned long long key = kk[i];
      bool match = (hib >= 64) || (((key ^ prefix) >> hib) == 0ull);
      if (match)
        atomicAdd(&hist[(unsigned)((key >> s) & ((1u << w) - 1u))], 1u);
    }
    __syncthreads();
    for (int off = 1; off < 2048; off <<= 1) {
      for (int b = tid; b < 2048; b += 1024)
        suf[b] = hist[b] + ((b + off < 2048) ? hist[b + off] : 0u);
      __syncthreads();
      for (int b = tid; b < 2048; b += 1024) hist[b] = suf[b];
      __syncthreads();
    }
    const int nb = 1 << w;
    for (int b = tid; b < nb; b += 1024) {
      unsigned int sv = hist[b];
      unsigned int nxt = (b + 1 < 2048) ? hist[b + 1] : 0u;
      if (sv >= (unsigned)need && nxt < (unsigned)need) selb = b;
    }
    __syncthreads();
    int bstar = selb;
    unsigned int cgt = (bstar + 1 < 2048) ? hist[bstar + 1] : 0u;
    need -= (int)cgt;
    prefix |= ((unsigned long long)bstar) << s;
    __syncthreads();
  }
  if (tid == 0) cnt = 0u;
  __syncthreads();
  for (int i = tid; i < NANCH; i += 1024) {
    unsigned long long key = kk[i];
    if (key >= prefix) {
      unsigned int pos = atomicAdd(&cnt, 1u);
      if (pos < 4096u) sb[pos] = ~key;
    }
  }
  __syncthreads();
  unsigned int c0 = cnt;
  for (int i = tid; i < 4096; i += 1024)
    if (i >= (int)c0) sb[i] = 0xFFFFFFFFFFFFFFFFull;
  __syncthreads();
  for (int k2 = 2; k2 <= 4096; k2 <<= 1) {
    for (int j = k2 >> 1; j > 0; j >>= 1) {
      for (int t = tid; t < 2048; t += 1024) {
        int i = ((t & ~(j - 1)) << 1) | (t & (j - 1));
        int pp = i + j;
        bool up = ((i & k2) == 0);
        unsigned long long va = sb[i], vb = sb[pp];
        bool sw = up ? (va > vb) : (va < vb);
        if (sw) { sb[i] = vb; sb[pp] = va; }
      }
      __syncthreads();
    }
  }
  const float4* bx = boxes + (size_t)n * NANCH;
  for (int r = tid; r < PRE_NMS_N; r += 1024) {
    unsigned long long key = ~sb[r];
    unsigned int idx = ~((unsigned int)(key & 0xFFFFFFFFull));
    sboxes[(size_t)n * PRE_NMS_N + r] = bx[idx];
    unsigned int hi32 = (unsigned int)(key >> 32);
    sfin[n * PRE_NMS_N + r] = (hi32 > 0x007FFFFFu) ? 1u : 0u;
  }
}

// ---------------- K5: suppression bitmask, pair-per-wave (uniform load) ---------------
__global__ __launch_bounds__(256) void k5_mask(
    const float4* __restrict__ sboxes, unsigned long long* __restrict__ mask) {
  const int n = blockIdx.y;
  const int wv = threadIdx.x >> 6, lane = threadIdx.x & 63;
  const int pid = blockIdx.x * 4 + wv;
  if (pid >= NPAIR) return;
  int c = 0, k = pid;
  while (k >= NWORD - c) { k -= NWORD - c; ++c; }
  const int wd = c + k;
  __shared__ float sA[4][64][5];
  const int j = wd * 64 + lane;
  float4 bj = sboxes[(size_t)n * PRE_NMS_N + ((j < PRE_NMS_N) ? j : 0)];
  const float aj = (bj.z - bj.x) * (bj.w - bj.y);
  const int ig = c * 64 + lane;
  float4 bi = sboxes[(size_t)n * PRE_NMS_N + ((ig < PRE_NMS_N) ? ig : 0)];
  sA[wv][lane][0] = bi.x; sA[wv][lane][1] = bi.y;
  sA[wv][lane][2] = bi.z; sA[wv][lane][3] = bi.w;
  sA[wv][lane][4] = (bi.z - bi.x) * (bi.w - bi.y);
  unsigned long long* mrow = mask + ((size_t)n * PRE_NMS_N + c * 64) * NWORD + wd;
  const int nrow = (c == NWORD - 1) ? (PRE_NMS_N - c * 64) : 64;
  for (int il = 0; il < nrow; ++il) {
    float iy1 = sA[wv][il][0], ix1 = sA[wv][il][1];
    float iy2 = sA[wv][il][2], ix2 = sA[wv][il][3], ia = sA[wv][il][4];
    float y1 = fmaxf(iy1, bj.x), x1 = fmaxf(ix1, bj.y);
    float y2 = fminf(iy2, bj.z), x2 = fminf(ix2, bj.w);
    float inter = fmaxf(y2 - y1, 0.f) * fmaxf(x2 - x1, 0.f);
    float uni = ia + aj - inter;
    float iou = (uni > 0.f) ? inter / uni : 0.f;
    bool pr = (j < PRE_NMS_N) && (iou > 0.7f);
    unsigned long long bits = __ballot(pr);
    if (lane == 0) mrow[(size_t)il * NWORD] = bits;
  }
}

// ---------------- K6: chunked greedy NMS, LDS-staged slabs, 256 thr, wave0 serial -----
__global__ __launch_bounds__(256) void k6_nms(
    const unsigned long long* __restrict__ mask, const float4* __restrict__ sboxes,
    const unsigned int* __restrict__ sfin,
    float* __restrict__ out_rois, float* __restrict__ out_valid) {
  const int n = blockIdx.x, tid = threadIdx.x;
  const int lane = tid & 63;
  const unsigned long long* M = mask + (size_t)n * PRE_NMS_N * NWORD;
  __shared__ unsigned long long rows[2][64][NWORD];
  __shared__ unsigned long long keepW[NWORD];

  #pragma unroll
  for (int j = 0; j < 12; ++j) {
    int idx = j * 256 + tid;
    if (idx < 64 * NWORD) {
      int row = idx / NWORD, w = idx - row * NWORD;
      rows[0][row][w] = M[(size_t)row * NWORD + w];
    }
  }
  __syncthreads();

  unsigned long long Rw = 0ull;
  for (int c = 0; c < NWORD; ++c) {
    const int buf = c & 1;
    const int i0 = c * 64;
    const int nIt = (c == NWORD - 1) ? (PRE_NMS_N - i0) : 64;
    unsigned long long pf[12];
    const bool hasNext = (c + 1 < NWORD);
    if (hasNext) {
      const int i1 = (c + 1) * 64;
      #pragma unroll
      for (int j = 0; j < 12; ++j) {
        int idx = j * 256 + tid;
        if (idx < 64 * NWORD) {
          int row = idx / NWORD, w = idx - row * NWORD;
          int gi = i1 + row;
          pf[j] = (gi < PRE_NMS_N) ? M[(size_t)gi * NWORD + w] : 0ull;
        }
      }
    }
    if (tid < 64) {
      unsigned long long Dcur = rows[buf][lane][c];
      unsigned long long rem = rdlane64(Rw, c);
      unsigned long long und = ~rem;
      if (nIt < 64) und &= ((1ull << nIt) - 1ull);
      unsigned long long kept = 0ull;
      while (und) {
        int b = __builtin_ctzll(und);
        kept |= (1ull << b);
        unsigned long long db = rdlane64(Dcur, b);
        und &= ~db;
        und &= ~(1ull << b);
      }
      if (lane == 0) keepW[c] = kept;
      const bool upd = (lane > c) && (lane < NWORD);
      unsigned long long kk = kept;
      while (kk) {
        int b0 = __builtin_ctzll(kk); kk &= kk - 1ull;
        int b1 = b0, b2 = b0, b3 = b0;
        if (kk) { b1 = __builtin_ctzll(kk); kk &= kk - 1ull; }
        if (kk) { b2 = __builtin_ctzll(kk); kk &= kk - 1ull; }
        if (kk) { b3 = __builtin_ctzll(kk); kk &= kk - 1ull; }
        if (upd) {
          unsigned long long v0 = rows[buf][b0][lane];
          unsigned long long v1 = rows[buf][b1][lane];
          unsigned long long v2 = rows[buf][b2][lane];
          unsigned long long v3 = rows[buf][b3][lane];
          Rw |= (v0 | v1) | (v2 | v3);
        }
      }
    }
    if (hasNext) {
      #pragma unroll
      for (int j = 0; j < 12; ++j) {
        int idx = j * 256 + tid;
        if (idx < 64 * NWORD) {
          int row = idx / NWORD, w = idx - row * NWORD;
          rows[buf ^ 1][row][w] = pf[j];
        }
      }
    }
    __syncthreads();
  }

  if (tid < 64) {
    const unsigned int* fin = sfin + n * PRE_NMS_N;
    int running = 0;
    for (int c = 0; c < NWORD; ++c) {
      int i = c * 64 + lane;
      unsigned long long kw = keepW[c];
      int kf = 0;
      if (i < PRE_NMS_N) kf = (int)((kw >> lane) & 1ull) & (fin[i] ? 1 : 0);
      unsigned long long m = __ballot(kf);
      if (kf) {
        int r = running + __popcll(m & ((1ull << lane) - 1ull));
        if (r < POST_NMS_N) {
          float4 b4 = sboxes[(size_t)n * PRE_NMS_N + i];
          float* o = out_rois + (size_t)(n * POST_NMS_N + r) * 4;
          o[0] = b4.x; o[1] = b4.y; o[2] = b4.z; o[3] = b4.w;
          out_valid[n * POST_NMS_N + r] = 1.0f;
        }
      }
      running += __popcll(m);
    }
    int keptTotal = running;
    if (keptTotal < POST_NMS_N) {
      int runN = 0;
      for (int c = 0; c < NWORD && keptTotal + runN < POST_NMS_N; ++c) {
        int i = c * 64 + lane;
        unsigned long long kw = keepW[c];
        int nf = 0;
        if (i < PRE_NMS_N) nf = !(((kw >> lane) & 1ull) && fin[i]);
        unsigned long long m = __ballot(nf);
        if (nf) {
          int r = keptTotal + runN + __popcll(m & ((1ull << lane) - 1ull));
          if (r < POST_NMS_N) {
            float* o = out_rois + (size_t)(n * POST_NMS_N + r) * 4;
            o[0] = 0.f; o[1] = 0.f; o[2] = 0.f; o[3] = 0.f;
            out_valid[n * POST_NMS_N + r] = 0.0f;
          }
        }
        runN += __popcll(m);
      }
    }
  }
}

extern "C" void kernel_launch(void* const* d_in, const int* in_sizes, int n_in,
                              void* d_out, int out_size, void* d_ws, size_t ws_size,
                              hipStream_t stream) {
  const float* x  = (const float*)d_in[0];
  const float* W1 = (const float*)d_in[1];
  const float* b1 = (const float*)d_in[2];
  const float* Ws = (const float*)d_in[3];
  const float* bs = (const float*)d_in[4];
  const float* Wl = (const float*)d_in[5];
  const float* bl = (const float*)d_in[6];
  const int* ihp  = (const int*)d_in[7];
  const int* iwp  = (const int*)d_in[8];

  float* out = (float*)d_out;
  float* o_locs   = out;
  float* o_scores = out + OFF_SCORES;
  float* o_rois   = out + OFF_ROIS;
  float* o_valid  = out + OFF_VALID;
  float* o_anch   = out + OFF_ANCH;

  char* ws = (char*)d_ws;
  const size_t OFF_WTH = 0;                  // 4,718,592
  const size_t OFF_WTL = 4718592;            // 4,718,592
  const size_t OFF_FG  = 9437184;            // 2,359,296
  const size_t OFF_DYN = 11796480;           // xh | xl | h (nipp images each)

  // images per phase: ws_size is constant per deployment -> same branch every call
  const size_t PER_IMG = 4460544ull * 2 + 8388608ull;   // xh + xl + h = 17,309,696
  int nipp;
  if (ws_size >= OFF_DYN + 4 * PER_IMG) nipp = 4;
  else if (ws_size >= OFF_DYN + 2 * PER_IMG) nipp = 2;
  else nipp = 1;
  const int nph = N_IMG / nipp;

  _Float16* wth = (_Float16*)(ws + OFF_WTH);
  _Float16* wtl = (_Float16*)(ws + OFF_WTL);
  float* fg     = (float*)(ws + OFF_FG);
  _Float16* xh  = (_Float16*)(ws + OFF_DYN);
  _Float16* xl  = (_Float16*)(ws + OFF_DYN + (size_t)nipp * 4460544);
  float* h      = (float*)(ws + OFF_DYN + (size_t)nipp * 8921088);

  float4* boxes            = (float4*)(ws + OFF_DYN);
  unsigned long long* keys = (unsigned long long*)(ws + OFF_DYN + 2359296);
  float4* sboxes           = (float4*)(ws + OFF_DYN + 3538944);
  unsigned int* sfin       = (unsigned int*)(ws + OFF_DYN + 3730944);
  unsigned long long* mask = (unsigned long long*)(ws + OFF_DYN + 3778944);

  k0w_convert<<<dim3(9, 16), 256, 0, stream>>>(W1, wth, wtl);

  for (int ph = 0; ph < nph; ++ph) {
    int img0 = ph * nipp;
    k0x_convert<<<dim3(69, 8, nipp), 256, 0, stream>>>(x, xh, xl, img0);
    k1_gemm<<<dim3(8, nipp * 32), 256, 0, stream>>>(xh, xl, wth, wtl, b1, h);
    k2_heads<<<dim3(nipp * 64), 256, 0, stream>>>(h, Wl, bl, Ws, bs,
                                                  o_locs, o_scores, fg, img0);
  }

  k3_decode<<<(N_IMG * NANCH + 255) / 256, 256, 0, stream>>>(o_locs, fg, ihp, iwp,
                                                             o_anch, boxes, keys);
  k4_select<<<4, 1024, 0, stream>>>(keys, boxes, sboxes, sfin);
  k5_mask<<<dim3((NPAIR + 3) / 4, 4), 256, 0, stream>>>(sboxes, mask);
  k6_nms<<<4, 256, 0, stream>>>(mask, sboxes, sfin, o_rois, o_valid);
}

// Round 9
// 760.972 us; speedup vs baseline: 3.2356x; 1.1359x over previous
//
#include <hip/hip_runtime.h>
#include <hip/hip_bf16.h>
#include <math.h>

#define N_IMG 4
#define CIN 512
#define NANCH 36864          // 64*64*9
#define PRE_NMS_N 3000
#define POST_NMS_N 300
#define NWORD 47             // ceil(3000/64)
#define NPAIR 1128           // NWORD*(NWORD+1)/2
#define PPX 4356             // 66*66 padded pixels

// out layout (floats)
#define OFF_SCORES 589824
#define OFF_ROIS   884736
#define OFF_VALID  889536
#define OFF_ANCH   890736

typedef _Float16 f16x8 __attribute__((ext_vector_type(8)));
typedef float f32x4 __attribute__((ext_vector_type(4)));

__device__ __forceinline__ int swz(int p) { return (p + (p >> 2)) & 3; }

__device__ __forceinline__ unsigned long long rdlane64(unsigned long long v, int l) {
  unsigned int lo = (unsigned int)__builtin_amdgcn_readlane((int)(unsigned int)v, l);
  unsigned int hi = (unsigned int)__builtin_amdgcn_readlane((int)(unsigned int)(v >> 32), l);
  return (((unsigned long long)hi) << 32) | lo;
}

// ---------------- K0w: W1 [co][ci][tap] -> Wt_{h,l}[tap][co][ci], scaled x64 ----------
__global__ __launch_bounds__(256) void k0w_convert(
    const float* __restrict__ W1, _Float16* __restrict__ wth, _Float16* __restrict__ wtl) {
  const int tap = blockIdx.x, co0 = blockIdx.y * 32;
  for (int idx = threadIdx.x; idx < 32 * 512; idx += 256) {
    int col = idx >> 9, ci = idx & 511;
    float v = W1[(size_t)(co0 + col) * 4608 + ci * 9 + tap] * 64.0f;
    _Float16 hi = (_Float16)v;
    float lo = v - (float)hi;
    size_t o = ((size_t)(tap * 512 + co0 + col) << 9) + ci;
    wth[o] = hi; wtl[o] = (_Float16)lo;
  }
}

// ---------------- K0x: x [ci][64x64] -> padded xh/xl [img_l][66*66][512] f16 split ----
__global__ __launch_bounds__(256) void k0x_convert(
    const float* __restrict__ x, _Float16* __restrict__ xh, _Float16* __restrict__ xl,
    int img0) {
  const int bx = blockIdx.x, ci0 = blockIdx.y * 64;
  const int img_l = blockIdx.z;
  const int img = img0 + img_l;
  const size_t sbase = (size_t)img_l * PPX;
  const int tid = threadIdx.x;
  if (bx < 64) {
    __shared__ float t[64][65];
    const float* xp = x + ((size_t)img * 512 + ci0) * 4096 + bx * 64;
    for (int idx = tid; idx < 4096; idx += 256) {
      int ci_l = idx >> 6, col = idx & 63;
      t[ci_l][col] = xp[(size_t)ci_l * 4096 + col];
    }
    __syncthreads();
    for (int idx = tid; idx < 4096; idx += 256) {
      int col = idx >> 6, ci_l = idx & 63;
      float v = t[ci_l][col];
      _Float16 hi = (_Float16)v;
      float lo = v - (float)hi;
      size_t o = ((sbase + (size_t)(bx + 1) * 66 + col + 1) << 9) + ci0 + ci_l;
      xh[o] = hi; xl[o] = (_Float16)lo;
    }
  } else {
    for (int tt = tid; tt < 52 * 64; tt += 256) {
      int pl = tt >> 6, ci_l = tt & 63;
      int p = (bx - 64) * 52 + pl;
      if (p < 260) {
        int pp;
        if (p < 66) pp = p;
        else if (p < 132) pp = 65 * 66 + (p - 66);
        else if (p < 196) pp = (p - 132 + 1) * 66;
        else pp = (p - 196 + 1) * 66 + 65;
        size_t o = ((sbase + pp) << 9) + ci0 + ci_l;
        xh[o] = (_Float16)0.f; xl[o] = (_Float16)0.f;
      }
    }
  }
}

// ---------------- K1: conv3x3 MFMA implicit GEMM, 128x128 block tile ------------------
// grid (4 co-groups, nipp*32 px-tiles): XCD = (co+4*px)%8 -> one 2.36MB W slice per XCD.
// Wave tile 64x64 (4x4 acc), 48 MFMA/iter/wave: matrix pipe >= LDS pipe.
// cb-outer/tap-inner; dist-1 prefetch; LDS-write AFTER MFMA.
__global__ __launch_bounds__(256, 2) void k1_gemm(
    const _Float16* __restrict__ xh, const _Float16* __restrict__ xl,
    const _Float16* __restrict__ wth, const _Float16* __restrict__ wtl,
    const float* __restrict__ b1, float* __restrict__ h_out) {
  const int tid = threadIdx.x;
  const int co0 = blockIdx.x * 128;
  const int px0 = blockIdx.y * 128;          // linear px across nipp images
  const int img_l = px0 >> 12;
  const int y0 = (px0 & 4095) >> 6;

  __shared__ __align__(16) _Float16 AsL[4][4096];   // [buf*2+hl][128px x 32ci]
  __shared__ __align__(16) _Float16 BsL[4][4096];   // [buf*2+hl][128co x 32ci]

  const int lane = tid & 63, q = lane >> 4, lr = lane & 15;
  const int wid = tid >> 6, wm = wid & 1, wn = wid >> 1;

  int abase[2], bbase[2];
  #pragma unroll
  for (int it = 0; it < 2; ++it) {
    int s = it * 256 + tid;
    int pxl = s >> 2, cpos = s & 3;
    int c = cpos ^ swz(pxl);
    int row = pxl >> 6, xcol = pxl & 63;
    abase[it] = ((img_l * PPX + (y0 + row) * 66 + xcol) << 9) + c * 8;
    int bcol = s >> 2;
    int bc = (s & 3) ^ swz(bcol);
    bbase[it] = ((co0 + bcol) << 9) + bc * 8;
  }

  const int DD[9] = {0, 1, 2, 66, 67, 68, 132, 133, 134};

  f32x4 acc[4][4] = {};
  float4 rah[2], ral[2], rbh[2], rbl[2];

  #pragma unroll
  for (int it = 0; it < 2; ++it) {
    rah[it] = *(const float4*)(xh + abase[it]);
    ral[it] = *(const float4*)(xl + abase[it]);
    rbh[it] = *(const float4*)(wth + bbase[it]);
    rbl[it] = *(const float4*)(wtl + bbase[it]);
  }
  #pragma unroll
  for (int it = 0; it < 2; ++it) {
    *(float4*)&AsL[0][(it * 256 + tid) * 8] = rah[it];
    *(float4*)&AsL[1][(it * 256 + tid) * 8] = ral[it];
    *(float4*)&BsL[0][(it * 256 + tid) * 8] = rbh[it];
    *(float4*)&BsL[1][(it * 256 + tid) * 8] = rbl[it];
  }

  int tap = 0, cb = 0;   // tap fastest (cb-outer)
  for (int t = 0; t < 144; ++t) {
    __syncthreads();
    const int buf = t & 1;
    if (t < 143) {
      int tapn = tap + 1, cbn = cb;
      if (tapn == 9) { tapn = 0; cbn = cb + 1; }
      int ad = (DD[tapn] << 9) + cbn * 32;
      int bd = tapn * 262144 + cbn * 32;
      #pragma unroll
      for (int it = 0; it < 2; ++it) {
        rah[it] = *(const float4*)(xh + abase[it] + ad);
        ral[it] = *(const float4*)(xl + abase[it] + ad);
        rbh[it] = *(const float4*)(wth + bbase[it] + bd);
        rbl[it] = *(const float4*)(wtl + bbase[it] + bd);
      }
    }
    f16x8 ah[4], al[4], bh[4], bl[4];
    #pragma unroll
    for (int mi = 0; mi < 4; ++mi) {
      int pxl = wm * 64 + mi * 16 + lr;
      int cpr = q ^ swz(pxl);
      ah[mi] = *(const f16x8*)&AsL[buf * 2 + 0][pxl * 32 + cpr * 8];
      al[mi] = *(const f16x8*)&AsL[buf * 2 + 1][pxl * 32 + cpr * 8];
    }
    #pragma unroll
    for (int ni = 0; ni < 4; ++ni) {
      int col = wn * 64 + ni * 16 + lr;
      int cpr = q ^ swz(col);
      bh[ni] = *(const f16x8*)&BsL[buf * 2 + 0][col * 32 + cpr * 8];
      bl[ni] = *(const f16x8*)&BsL[buf * 2 + 1][col * 32 + cpr * 8];
    }
    #pragma unroll
    for (int mi = 0; mi < 4; ++mi)
      #pragma unroll
      for (int ni = 0; ni < 4; ++ni) {
        acc[mi][ni] = __builtin_amdgcn_mfma_f32_16x16x32_f16(ah[mi], bh[ni], acc[mi][ni], 0, 0, 0);
        acc[mi][ni] = __builtin_amdgcn_mfma_f32_16x16x32_f16(ah[mi], bl[ni], acc[mi][ni], 0, 0, 0);
        acc[mi][ni] = __builtin_amdgcn_mfma_f32_16x16x32_f16(al[mi], bh[ni], acc[mi][ni], 0, 0, 0);
      }
    if (t < 143) {
      int nb = (t + 1) & 1;
      #pragma unroll
      for (int it = 0; it < 2; ++it) {
        *(float4*)&AsL[nb * 2 + 0][(it * 256 + tid) * 8] = rah[it];
        *(float4*)&AsL[nb * 2 + 1][(it * 256 + tid) * 8] = ral[it];
        *(float4*)&BsL[nb * 2 + 0][(it * 256 + tid) * 8] = rbh[it];
        *(float4*)&BsL[nb * 2 + 1][(it * 256 + tid) * 8] = rbl[it];
      }
    }
    ++tap;
    if (tap == 9) { tap = 0; ++cb; }
  }

  float bb[4];
  #pragma unroll
  for (int ni = 0; ni < 4; ++ni) bb[ni] = b1[co0 + wn * 64 + ni * 16 + lr];
  #pragma unroll
  for (int mi = 0; mi < 4; ++mi)
    #pragma unroll
    for (int ni = 0; ni < 4; ++ni)
      #pragma unroll
      for (int rr = 0; rr < 4; ++rr) {
        int pxl = wm * 64 + mi * 16 + q * 4 + rr;
        int co = co0 + wn * 64 + ni * 16 + lr;
        float v = acc[mi][ni][rr] * 0.015625f + bb[ni];
        h_out[((size_t)(px0 + pxl) << 9) + co] = fmaxf(v, 0.f);
      }
}

// ---------------- K2: 1x1 heads + softmax-fg, K-split x4 (multi-img linear px) --------
__global__ __launch_bounds__(256) void k2_heads(
    const float* __restrict__ h,
    const float* __restrict__ Wl, const float* __restrict__ bl,
    const float* __restrict__ Ws, const float* __restrict__ bs,
    float* __restrict__ rpn_locs, float* __restrict__ rpn_scores,
    float* __restrict__ fg, int img0) {
  const int tid = threadIdx.x;
  const int px0 = blockIdx.x * 64;           // linear px across nipp images
  const int pxl = tid & 63, kq = tid >> 6;
  __shared__ float part[4][64][57];
  float acc[54];
  #pragma unroll
  for (int c = 0; c < 54; ++c) acc[c] = 0.f;
  const float* hp = h + ((size_t)(px0 + pxl) << 9) + kq * 128;
  for (int k = 0; k < 128; k += 4) {
    float4 a = *(const float4*)(hp + k);
    #pragma unroll
    for (int ch = 0; ch < 54; ++ch) {
      const float* wr = (ch < 36) ? (Wl + ch * 512) : (Ws + (ch - 36) * 512);
      float4 w = *(const float4*)(wr + kq * 128 + k);
      acc[ch] = fmaf(w.x, a.x, fmaf(w.y, a.y, fmaf(w.z, a.z, fmaf(w.w, a.w, acc[ch]))));
    }
  }
  #pragma unroll
  for (int ch = 0; ch < 54; ++ch) part[kq][pxl][ch] = acc[ch];
  __syncthreads();

  const int cq = kq;
  const int p = px0 + pxl;
  const int img = img0 + (p >> 12);
  const int p_loc = p & 4095;
  const size_t abase = (size_t)img * NANCH + (size_t)p_loc * 9;
  if (cq < 3) {
    #pragma unroll
    for (int ai = 0; ai < 3; ++ai) {
      int a = cq * 3 + ai;
      float v[4];
      #pragma unroll
      for (int c = 0; c < 4; ++c) {
        int ch = a * 4 + c;
        v[c] = ((part[0][pxl][ch] + part[1][pxl][ch]) + part[2][pxl][ch]) +
               part[3][pxl][ch] + bl[ch];
      }
      float4 lv; lv.x = v[0]; lv.y = v[1]; lv.z = v[2]; lv.w = v[3];
      *(float4*)(rpn_locs + (abase + a) * 4) = lv;
    }
  } else {
    #pragma unroll
    for (int a = 0; a < 9; ++a) {
      int c0 = 36 + 2 * a, c1 = c0 + 1;
      float s0 = ((part[0][pxl][c0] + part[1][pxl][c0]) + part[2][pxl][c0]) +
                 part[3][pxl][c0] + bs[2 * a];
      float s1 = ((part[0][pxl][c1] + part[1][pxl][c1]) + part[2][pxl][c1]) +
                 part[3][pxl][c1] + bs[2 * a + 1];
      float2 sv; sv.x = s0; sv.y = s1;
      *(float2*)(rpn_scores + (abase + a) * 2) = sv;
      float m = fmaxf(s0, s1);
      float e0 = expf(s0 - m), e1 = expf(s1 - m);
      fg[abase + a] = e1 / (e0 + e1);
    }
  }
}

// ---------------- K3: anchors + decode + clip + key ----------------
__global__ void k3_decode(
    const float* __restrict__ locs, const float* __restrict__ fg,
    const int* __restrict__ ihp, const int* __restrict__ iwp,
    float* __restrict__ anchors_out, float4* __restrict__ boxes,
    unsigned long long* __restrict__ keys) {
  int gid = blockIdx.x * 256 + threadIdx.x;
  if (gid >= N_IMG * NANCH) return;
  int n = gid / NANCH, i = gid - n * NANCH;
  int p = i / 9, a = i - p * 9;
  int yy = p >> 6, xx = p & 63;
  int ri = a / 3, si = a - ri * 3;
  const float ratios[3] = {0.5f, 1.0f, 2.0f};
  const float scales[3] = {8.f, 16.f, 32.f};
  float hh = 16.f * scales[si] * sqrtf(ratios[ri]);
  float ww = 16.f * scales[si] * sqrtf(1.0f / ratios[ri]);
  float by1 = 8.f - hh * 0.5f, bx1 = 8.f - ww * 0.5f;
  float by2 = 8.f + hh * 0.5f, bx2 = 8.f + ww * 0.5f;
  float ay1 = yy * 16.f + by1, ax1 = xx * 16.f + bx1;
  float ay2 = yy * 16.f + by2, ax2 = xx * 16.f + bx2;
  if (n == 0) {
    float* ao = anchors_out + (size_t)i * 4;
    ao[0] = ay1; ao[1] = ax1; ao[2] = ay2; ao[3] = ax2;
  }
  const float* lp = locs + ((size_t)n * NANCH + i) * 4;
  float dy = lp[0], dx = lp[1], dh = lp[2], dw = lp[3];
  float ah = ay2 - ay1, aw = ax2 - ax1;
  float acy = ay1 + 0.5f * ah, acx = ax1 + 0.5f * aw;
  float cy = dy * ah + acy, cx = dx * aw + acx;
  float hb = expf(dh) * ah, wb = expf(dw) * aw;
  float imh = (float)ihp[0], imw = (float)iwp[0];
  float y1 = fminf(fmaxf(cy - 0.5f * hb, 0.f), imh);
  float x1 = fminf(fmaxf(cx - 0.5f * wb, 0.f), imw);
  float y2 = fminf(fmaxf(cy + 0.5f * hb, 0.f), imh);
  float x2 = fminf(fmaxf(cx + 0.5f * wb, 0.f), imw);
  bool valid = ((y2 - y1) >= 16.0f) && ((x2 - x1) >= 16.0f);
  float s = valid ? fg[(size_t)n * NANCH + i] : -__builtin_inff();
  boxes[(size_t)n * NANCH + i] = make_float4(y1, x1, y2, x2);
  unsigned int fb = __float_as_uint(s);
  unsigned int mono = (fb & 0x80000000u) ? ~fb : (fb | 0x80000000u);
  keys[(size_t)n * NANCH + i] =
      (((unsigned long long)mono) << 32) | (unsigned int)(~(unsigned int)i);
}

// ---------------- K4: per-image exact top-3000 (sorted desc) ----------------
__global__ __launch_bounds__(1024) void k4_select(
    const unsigned long long* __restrict__ keys, const float4* __restrict__ boxes,
    float4* __restrict__ sboxes, unsigned int* __restrict__ sfin) {
  const int n = blockIdx.x, tid = threadIdx.x;
  const unsigned long long* kk = keys + (size_t)n * NANCH;
  __shared__ unsigned int hist[2048];
  __shared__ unsigned int suf[2048];
  __shared__ unsigned long long sb[4096];
  __shared__ int selb;
  __shared__ unsigned int cnt;
  unsigned long long prefix = 0ull;
  int need = PRE_NMS_N;
  const int shifts[6] = {53, 42, 31, 20, 10, 0};
  const int widths[6] = {11, 11, 11, 11, 10, 10};
  for (int rd = 0; rd < 6; ++rd) {
    const int s = shifts[rd], w = widths[rd];
    const int hib = s + w;
    for (int b = tid; b < 2048; b += 1024) hist[b] = 0u;
    __syncthreads();
    for (int i = tid; i < NANCH; i += 1024) {
      unsigned long long key = kk[i];
      bool match = (hib >= 64) || (((key ^ prefix) >> hib) == 0ull);
      if (match)
        atomicAdd(&hist[(unsigned)((key >> s) & ((1u << w) - 1u))], 1u);
    }
    __syncthreads();
    for (int off = 1; off < 2048; off <<= 1) {
      for (int b = tid; b < 2048; b += 1024)
        suf[b] = hist[b] + ((b + off < 2048) ? hist[b + off] : 0u);
      __syncthreads();
      for (int b = tid; b < 2048; b += 1024) hist[b] = suf[b];
      __syncthreads();
    }
    const int nb = 1 << w;
    for (int b = tid; b < nb; b += 1024) {
      unsigned int sv = hist[b];
      unsigned int nxt = (b + 1 < 2048) ? hist[b + 1] : 0u;
      if (sv >= (unsigned)need && nxt < (unsigned)need) selb = b;
    }
    __syncthreads();
    int bstar = selb;
    unsigned int cgt = (bstar + 1 < 2048) ? hist[bstar + 1] : 0u;
    need -= (int)cgt;
    prefix |= ((unsigned long long)bstar) << s;
    __syncthreads();
  }
  if (tid == 0) cnt = 0u;
  __syncthreads();
  for (int i = tid; i < NANCH; i += 1024) {
    unsigned long long key = kk[i];
    if (key >= prefix) {
      unsigned int pos = atomicAdd(&cnt, 1u);
      if (pos < 4096u) sb[pos] = ~key;
    }
  }
  __syncthreads();
  unsigned int c0 = cnt;
  for (int i = tid; i < 4096; i += 1024)
    if (i >= (int)c0) sb[i] = 0xFFFFFFFFFFFFFFFFull;
  __syncthreads();
  for (int k2 = 2; k2 <= 4096; k2 <<= 1) {
    for (int j = k2 >> 1; j > 0; j >>= 1) {
      for (int t = tid; t < 2048; t += 1024) {
        int i = ((t & ~(j - 1)) << 1) | (t & (j - 1));
        int pp = i + j;
        bool up = ((i & k2) == 0);
        unsigned long long va = sb[i], vb = sb[pp];
        bool sw = up ? (va > vb) : (va < vb);
        if (sw) { sb[i] = vb; sb[pp] = va; }
      }
      __syncthreads();
    }
  }
  const float4* bx = boxes + (size_t)n * NANCH;
  for (int r = tid; r < PRE_NMS_N; r += 1024) {
    unsigned long long key = ~sb[r];
    unsigned int idx = ~((unsigned int)(key & 0xFFFFFFFFull));
    sboxes[(size_t)n * PRE_NMS_N + r] = bx[idx];
    unsigned int hi32 = (unsigned int)(key >> 32);
    sfin[n * PRE_NMS_N + r] = (hi32 > 0x007FFFFFu) ? 1u : 0u;
  }
}

// ---------------- K5: suppression bitmask, pair-per-wave (uniform load) ---------------
__global__ __launch_bounds__(256) void k5_mask(
    const float4* __restrict__ sboxes, unsigned long long* __restrict__ mask) {
  const int n = blockIdx.y;
  const int wv = threadIdx.x >> 6, lane = threadIdx.x & 63;
  const int pid = blockIdx.x * 4 + wv;
  if (pid >= NPAIR) return;
  int c = 0, k = pid;
  while (k >= NWORD - c) { k -= NWORD - c; ++c; }
  const int wd = c + k;
  __shared__ float sA[4][64][5];
  const int j = wd * 64 + lane;
  float4 bj = sboxes[(size_t)n * PRE_NMS_N + ((j < PRE_NMS_N) ? j : 0)];
  const float aj = (bj.z - bj.x) * (bj.w - bj.y);
  const int ig = c * 64 + lane;
  float4 bi = sboxes[(size_t)n * PRE_NMS_N + ((ig < PRE_NMS_N) ? ig : 0)];
  sA[wv][lane][0] = bi.x; sA[wv][lane][1] = bi.y;
  sA[wv][lane][2] = bi.z; sA[wv][lane][3] = bi.w;
  sA[wv][lane][4] = (bi.z - bi.x) * (bi.w - bi.y);
  unsigned long long* mrow = mask + ((size_t)n * PRE_NMS_N + c * 64) * NWORD + wd;
  const int nrow = (c == NWORD - 1) ? (PRE_NMS_N - c * 64) : 64;
  for (int il = 0; il < nrow; ++il) {
    float iy1 = sA[wv][il][0], ix1 = sA[wv][il][1];
    float iy2 = sA[wv][il][2], ix2 = sA[wv][il][3], ia = sA[wv][il][4];
    float y1 = fmaxf(iy1, bj.x), x1 = fmaxf(ix1, bj.y);
    float y2 = fminf(iy2, bj.z), x2 = fminf(ix2, bj.w);
    float inter = fmaxf(y2 - y1, 0.f) * fmaxf(x2 - x1, 0.f);
    float uni = ia + aj - inter;
    float iou = (uni > 0.f) ? inter / uni : 0.f;
    bool pr = (j < PRE_NMS_N) && (iou > 0.7f);
    unsigned long long bits = __ballot(pr);
    if (lane == 0) mrow[(size_t)il * NWORD] = bits;
  }
}

// ---------------- K6: chunked greedy NMS, LDS-staged slabs, 256 thr, wave0 serial -----
__global__ __launch_bounds__(256) void k6_nms(
    const unsigned long long* __restrict__ mask, const float4* __restrict__ sboxes,
    const unsigned int* __restrict__ sfin,
    float* __restrict__ out_rois, float* __restrict__ out_valid) {
  const int n = blockIdx.x, tid = threadIdx.x;
  const int lane = tid & 63;
  const unsigned long long* M = mask + (size_t)n * PRE_NMS_N * NWORD;
  __shared__ unsigned long long rows[2][64][NWORD];
  __shared__ unsigned long long keepW[NWORD];

  #pragma unroll
  for (int j = 0; j < 12; ++j) {
    int idx = j * 256 + tid;
    if (idx < 64 * NWORD) {
      int row = idx / NWORD, w = idx - row * NWORD;
      rows[0][row][w] = M[(size_t)row * NWORD + w];
    }
  }
  __syncthreads();

  unsigned long long Rw = 0ull;
  for (int c = 0; c < NWORD; ++c) {
    const int buf = c & 1;
    const int i0 = c * 64;
    const int nIt = (c == NWORD - 1) ? (PRE_NMS_N - i0) : 64;
    unsigned long long pf[12];
    const bool hasNext = (c + 1 < NWORD);
    if (hasNext) {
      const int i1 = (c + 1) * 64;
      #pragma unroll
      for (int j = 0; j < 12; ++j) {
        int idx = j * 256 + tid;
        if (idx < 64 * NWORD) {
          int row = idx / NWORD, w = idx - row * NWORD;
          int gi = i1 + row;
          pf[j] = (gi < PRE_NMS_N) ? M[(size_t)gi * NWORD + w] : 0ull;
        }
      }
    }
    if (tid < 64) {
      unsigned long long Dcur = rows[buf][lane][c];
      unsigned long long rem = rdlane64(Rw, c);
      unsigned long long und = ~rem;
      if (nIt < 64) und &= ((1ull << nIt) - 1ull);
      unsigned long long kept = 0ull;
      while (und) {
        int b = __builtin_ctzll(und);
        kept |= (1ull << b);
        unsigned long long db = rdlane64(Dcur, b);
        und &= ~db;
        und &= ~(1ull << b);
      }
      if (lane == 0) keepW[c] = kept;
      const bool upd = (lane > c) && (lane < NWORD);
      unsigned long long kk = kept;
      while (kk) {
        int b0 = __builtin_ctzll(kk); kk &= kk - 1ull;
        int b1 = b0, b2 = b0, b3 = b0;
        if (kk) { b1 = __builtin_ctzll(kk); kk &= kk - 1ull; }
        if (kk) { b2 = __builtin_ctzll(kk); kk &= kk - 1ull; }
        if (kk) { b3 = __builtin_ctzll(kk); kk &= kk - 1ull; }
        if (upd) {
          unsigned long long v0 = rows[buf][b0][lane];
          unsigned long long v1 = rows[buf][b1][lane];
          unsigned long long v2 = rows[buf][b2][lane];
          unsigned long long v3 = rows[buf][b3][lane];
          Rw |= (v0 | v1) | (v2 | v3);
        }
      }
    }
    if (hasNext) {
      #pragma unroll
      for (int j = 0; j < 12; ++j) {
        int idx = j * 256 + tid;
        if (idx < 64 * NWORD) {
          int row = idx / NWORD, w = idx - row * NWORD;
          rows[buf ^ 1][row][w] = pf[j];
        }
      }
    }
    __syncthreads();
  }

  if (tid < 64) {
    const unsigned int* fin = sfin + n * PRE_NMS_N;
    int running = 0;
    for (int c = 0; c < NWORD; ++c) {
      int i = c * 64 + lane;
      unsigned long long kw = keepW[c];
      int kf = 0;
      if (i < PRE_NMS_N) kf = (int)((kw >> lane) & 1ull) & (fin[i] ? 1 : 0);
      unsigned long long m = __ballot(kf);
      if (kf) {
        int r = running + __popcll(m & ((1ull << lane) - 1ull));
        if (r < POST_NMS_N) {
          float4 b4 = sboxes[(size_t)n * PRE_NMS_N + i];
          float* o = out_rois + (size_t)(n * POST_NMS_N + r) * 4;
          o[0] = b4.x; o[1] = b4.y; o[2] = b4.z; o[3] = b4.w;
          out_valid[n * POST_NMS_N + r] = 1.0f;
        }
      }
      running += __popcll(m);
    }
    int keptTotal = running;
    if (keptTotal < POST_NMS_N) {
      int runN = 0;
      for (int c = 0; c < NWORD && keptTotal + runN < POST_NMS_N; ++c) {
        int i = c * 64 + lane;
        unsigned long long kw = keepW[c];
        int nf = 0;
        if (i < PRE_NMS_N) nf = !(((kw >> lane) & 1ull) && fin[i]);
        unsigned long long m = __ballot(nf);
        if (nf) {
          int r = keptTotal + runN + __popcll(m & ((1ull << lane) - 1ull));
          if (r < POST_NMS_N) {
            float* o = out_rois + (size_t)(n * POST_NMS_N + r) * 4;
            o[0] = 0.f; o[1] = 0.f; o[2] = 0.f; o[3] = 0.f;
            out_valid[n * POST_NMS_N + r] = 0.0f;
          }
        }
        runN += __popcll(m);
      }
    }
  }
}

extern "C" void kernel_launch(void* const* d_in, const int* in_sizes, int n_in,
                              void* d_out, int out_size, void* d_ws, size_t ws_size,
                              hipStream_t stream) {
  const float* x  = (const float*)d_in[0];
  const float* W1 = (const float*)d_in[1];
  const float* b1 = (const float*)d_in[2];
  const float* Ws = (const float*)d_in[3];
  const float* bs = (const float*)d_in[4];
  const float* Wl = (const float*)d_in[5];
  const float* bl = (const float*)d_in[6];
  const int* ihp  = (const int*)d_in[7];
  const int* iwp  = (const int*)d_in[8];

  float* out = (float*)d_out;
  float* o_locs   = out;
  float* o_scores = out + OFF_SCORES;
  float* o_rois   = out + OFF_ROIS;
  float* o_valid  = out + OFF_VALID;
  float* o_anch   = out + OFF_ANCH;

  char* ws = (char*)d_ws;
  const size_t OFF_WTH = 0;                  // 4,718,592
  const size_t OFF_WTL = 4718592;            // 4,718,592
  const size_t OFF_FG  = 9437184;            // 2,359,296
  const size_t OFF_DYN = 11796480;           // xh | xl | h (nipp images each)

  // images per phase: ws_size is constant per deployment -> same branch every call
  const size_t PER_IMG = 4460544ull * 2 + 8388608ull;   // xh + xl + h = 17,309,696
  int nipp;
  if (ws_size >= OFF_DYN + 4 * PER_IMG) nipp = 4;
  else if (ws_size >= OFF_DYN + 2 * PER_IMG) nipp = 2;
  else nipp = 1;
  const int nph = N_IMG / nipp;

  _Float16* wth = (_Float16*)(ws + OFF_WTH);
  _Float16* wtl = (_Float16*)(ws + OFF_WTL);
  float* fg     = (float*)(ws + OFF_FG);
  _Float16* xh  = (_Float16*)(ws + OFF_DYN);
  _Float16* xl  = (_Float16*)(ws + OFF_DYN + (size_t)nipp * 4460544);
  float* h      = (float*)(ws + OFF_DYN + (size_t)nipp * 8921088);

  float4* boxes            = (float4*)(ws + OFF_DYN);
  unsigned long long* keys = (unsigned long long*)(ws + OFF_DYN + 2359296);
  float4* sboxes           = (float4*)(ws + OFF_DYN + 3538944);
  unsigned int* sfin       = (unsigned int*)(ws + OFF_DYN + 3730944);
  unsigned long long* mask = (unsigned long long*)(ws + OFF_DYN + 3778944);

  k0w_convert<<<dim3(9, 16), 256, 0, stream>>>(W1, wth, wtl);

  for (int ph = 0; ph < nph; ++ph) {
    int img0 = ph * nipp;
    k0x_convert<<<dim3(69, 8, nipp), 256, 0, stream>>>(x, xh, xl, img0);
    k1_gemm<<<dim3(4, nipp * 32), 256, 0, stream>>>(xh, xl, wth, wtl, b1, h);
    k2_heads<<<dim3(nipp * 64), 256, 0, stream>>>(h, Wl, bl, Ws, bs,
                                                  o_locs, o_scores, fg, img0);
  }

  k3_decode<<<(N_IMG * NANCH + 255) / 256, 256, 0, stream>>>(o_locs, fg, ihp, iwp,
                                                             o_anch, boxes, keys);
  k4_select<<<4, 1024, 0, stream>>>(keys, boxes, sboxes, sfin);
  k5_mask<<<dim3((NPAIR + 3) / 4, 4), 256, 0, stream>>>(sboxes, mask);
  k6_nms<<<4, 256, 0, stream>>>(mask, sboxes, sfin, o_rois, o_valid);
}